// Round 1
// baseline (2566.596 us; speedup 1.0000x reference)
//
#include <hip/hip_runtime.h>

#define B_   32
#define T_   512
#define D_   256
#define C_   64
#define R_   4
#define RD_  64
#define OUT_ 256
#define MSTRIDE 68   // padded row stride for sh_m (16B-aligned, breaks pow2 banks)

// ---------------------------------------------------------------------------
// lgkm-only barrier: publishes LDS writes without draining vmcnt (keeps the
// global prefetch loads in flight across phase barriers).
__device__ __forceinline__ void bar_lds() {
  asm volatile("s_waitcnt lgkmcnt(0)" ::: "memory");
  __builtin_amdgcn_s_barrier();
  asm volatile("" ::: "memory");
}

__device__ __forceinline__ float wave_sum(float v) {
  v += __shfl_xor(v, 1);
  v += __shfl_xor(v, 2);
  v += __shfl_xor(v, 4);
  v += __shfl_xor(v, 8);
  v += __shfl_xor(v, 16);
  v += __shfl_xor(v, 32);
  return v;
}

// ---------------------------------------------------------------------------
// Xpre = X @ W   (16384 x 256) @ (256 x 256), f32
__global__ __launch_bounds__(256) void xpre_kernel(const float* __restrict__ X,
                                                   const float* __restrict__ W,
                                                   float* __restrict__ XP) {
  __shared__ __align__(16) float xs[32][D_];
  const int j = threadIdx.x;
  const int row0 = blockIdx.x * 32;
  for (int k = 0; k < 32; ++k)
    xs[k][j] = X[(size_t)(row0 + k) * D_ + j];
  __syncthreads();
  float acc[32];
#pragma unroll
  for (int k = 0; k < 32; ++k) acc[k] = 0.f;
  for (int d4 = 0; d4 < D_ / 4; ++d4) {
    const float w0 = W[(d4 * 4 + 0) * OUT_ + j];
    const float w1 = W[(d4 * 4 + 1) * OUT_ + j];
    const float w2 = W[(d4 * 4 + 2) * OUT_ + j];
    const float w3 = W[(d4 * 4 + 3) * OUT_ + j];
#pragma unroll
    for (int k = 0; k < 32; ++k) {
      const float4 x4 = *(const float4*)&xs[k][d4 * 4];
      acc[k] = fmaf(x4.x, w0, fmaf(x4.y, w1, fmaf(x4.z, w2, fmaf(x4.w, w3, acc[k]))));
    }
  }
  for (int k = 0; k < 32; ++k)
    XP[(size_t)(row0 + k) * OUT_ + j] = acc[k];
}

// ---------------------------------------------------------------------------
// Main recurrent kernel: one block per batch element, 1024 threads.
__global__ __launch_bounds__(1024) void gru_kernel(
    const float* __restrict__ X, const int* __restrict__ M,
    const int* __restrict__ Ei, const int* __restrict__ Eo,
    const int* __restrict__ Ri, const int* __restrict__ Ro,
    const float* __restrict__ U, const float* __restrict__ Bv,
    const float* __restrict__ Watt, const float* __restrict__ XP,
    float* __restrict__ outs, float* __restrict__ mems,
    float* __restrict__ aggs) {
  __shared__ __align__(16) float sh_x[2][D_];
  __shared__ __align__(16) float sh_xp[2][OUT_];
  __shared__ int sh_ri[2][C_];
  __shared__ int sh_ro[2][C_];
  __shared__ int sh_ei[2][C_];
  __shared__ int sh_eo[2][C_];
  __shared__ __align__(16) float sh_watt[R_][D_];
  __shared__ __align__(16) float sh_b[OUT_];
  __shared__ __align__(16) float sh_h[OUT_];
  __shared__ __align__(16) float sh_m[C_][MSTRIDE];
  __shared__ float sh_al[C_];
  __shared__ __align__(16) float sh_prev[OUT_];
  __shared__ __align__(16) float sh_hnew[OUT_];
  __shared__ __align__(16) float sh_pA[4][OUT_];
  __shared__ __align__(16) float sh_pB[4][OUT_];

  const int tid = threadIdx.x;
  const int lane = tid & 63;
  const int w = tid >> 6;
  const int j = tid & 255;
  const int kq = tid >> 8;
  const int b = blockIdx.x;
  const size_t bt0 = (size_t)b * T_;

  // U chunk into registers: ureg[i] = U[kq*64+i][j]
  float ureg[64];
#pragma unroll
  for (int i = 0; i < 64; ++i)
    ureg[i] = U[(size_t)(kq * 64 + i) * OUT_ + j];

  // static LDS
  ((float*)sh_watt)[tid] = Watt[tid];
  if (tid < OUT_) {
    sh_b[tid] = Bv[tid];
    sh_h[tid] = 0.f;
  }
  for (int idx = tid; idx < C_ * RD_; idx += 1024)
    sh_m[idx >> 6][idx & 63] = 0.f;
  // t = 0 inputs
  {
    const size_t bt = bt0;
    if (tid < D_) sh_x[0][tid] = X[bt * D_ + tid];
    else if (tid < 2 * D_) sh_xp[0][tid - D_] = XP[bt * OUT_ + (tid - D_)];
    else if (tid < 2 * D_ + C_) sh_ri[0][tid - 2 * D_] = Ri[bt * C_ + (tid - 2 * D_)];
    else if (tid < 2 * D_ + 2 * C_) sh_ro[0][tid - (2 * D_ + C_)] = Ro[bt * C_ + (tid - (2 * D_ + C_))];
    else if (tid < 2 * D_ + 3 * C_) sh_ei[0][tid - (2 * D_ + 2 * C_)] = Ei[bt * C_ + (tid - (2 * D_ + 2 * C_))];
    else if (tid < 2 * D_ + 4 * C_) sh_eo[0][tid - (2 * D_ + 3 * C_)] = Eo[bt * C_ + (tid - (2 * D_ + 3 * C_))];
  }
  float mcur = (float)M[bt0];
  float mnext = 0.f;
  __syncthreads();

  float4 xpref = {0.f, 0.f, 0.f, 0.f};
  float4 xppref = {0.f, 0.f, 0.f, 0.f};
  int ripref = 0, ropref = 0, eipref = 0, eopref = 0;

  for (int t = 0; t < T_; ++t) {
    const int buf = t & 1, nbuf = buf ^ 1;
    const size_t bt = bt0 + t;
    const bool hasnext = (t + 1 < T_);

    // -------- P1: attention (wave 0) + prefetch issue (waves 4-7) --------
    if (w == 0) {
      const float4 x4 = *(const float4*)&sh_x[buf][lane * 4];
      const float4 w0 = *(const float4*)&sh_watt[0][lane * 4];
      const float4 w1 = *(const float4*)&sh_watt[1][lane * 4];
      const float4 w2 = *(const float4*)&sh_watt[2][lane * 4];
      const float4 w3 = *(const float4*)&sh_watt[3][lane * 4];
      float y0 = fmaf(x4.x, w0.x, fmaf(x4.y, w0.y, fmaf(x4.z, w0.z, x4.w * w0.w)));
      float y1 = fmaf(x4.x, w1.x, fmaf(x4.y, w1.y, fmaf(x4.z, w1.z, x4.w * w1.w)));
      float y2 = fmaf(x4.x, w2.x, fmaf(x4.y, w2.y, fmaf(x4.z, w2.z, x4.w * w2.w)));
      float y3 = fmaf(x4.x, w3.x, fmaf(x4.y, w3.y, fmaf(x4.z, w3.z, x4.w * w3.w)));
      y0 = wave_sum(y0);
      y1 = wave_sum(y1);
      y2 = wave_sum(y2);
      y3 = wave_sum(y3);
      const int ric = sh_ri[buf][lane];
      const float eic = (float)sh_ei[buf][lane];
      float yv = (ric & 1) ? y1 : y0;
      const float yw = (ric & 1) ? y3 : y2;
      yv = (ric & 2) ? yw : yv;
      const float am = __expf(yv) * eic;  // EPS=1e-100 underflows to 0 in f32
      const float tot = wave_sum(am);
      const float alpha = am / tot;
      sh_al[lane] = alpha;
#pragma unroll
      for (int r = 0; r < R_; ++r) {
        float v = (ric == r) ? alpha : 0.f;
        v = wave_sum(v);
        if (lane == r) aggs[bt * R_ + r] = v;
      }
    } else if (w == 4) {
      if (hasnext) xpref = *(const float4*)&X[(bt + 1) * D_ + lane * 4];
    } else if (w == 5) {
      if (hasnext) xppref = *(const float4*)&XP[(bt + 1) * OUT_ + lane * 4];
    } else if (w == 6) {
      if (hasnext) {
        ripref = Ri[(bt + 1) * C_ + lane];
        ropref = Ro[(bt + 1) * C_ + lane];
      }
    } else if (w == 7) {
      if (hasnext) {
        eipref = Ei[(bt + 1) * C_ + lane];
        eopref = Eo[(bt + 1) * C_ + lane];
      }
    }
    if (hasnext) mnext = (float)M[bt + 1];
    bar_lds();

    // -------- P2: prev partials (waves 0-3, cq = wave id) --------
    if (w < 4) {
      const int r = lane >> 4, d4 = lane & 15;
      float4 acc = {0.f, 0.f, 0.f, 0.f};
#pragma unroll
      for (int ci = 0; ci < 16; ++ci) {
        const int c = w * 16 + ci;
        if (sh_ri[buf][c] == r) {
          const float a = sh_al[c];
          const float4 m4 = *(const float4*)&sh_m[c][d4 * 4];
          acc.x = fmaf(a, m4.x, acc.x);
          acc.y = fmaf(a, m4.y, acc.y);
          acc.z = fmaf(a, m4.z, acc.z);
          acc.w = fmaf(a, m4.w, acc.w);
        }
      }
      *(float4*)&sh_pA[w][lane * 4] = acc;
    }
    bar_lds();

    // -------- P3: finalize prev (wave 0) --------
    if (w == 0) {
      const float4 a0 = *(const float4*)&sh_pA[0][lane * 4];
      const float4 a1 = *(const float4*)&sh_pA[1][lane * 4];
      const float4 a2 = *(const float4*)&sh_pA[2][lane * 4];
      const float4 a3 = *(const float4*)&sh_pA[3][lane * 4];
      float4 p;
      p.x = (a0.x + a1.x) + (a2.x + a3.x);
      p.y = (a0.y + a1.y) + (a2.y + a3.y);
      p.z = (a0.z + a1.z) + (a2.z + a3.z);
      p.w = (a0.w + a1.w) + (a2.w + a3.w);
      *(float4*)&sh_prev[lane * 4] = p;
    }
    bar_lds();

    // -------- P4: h2h = prev @ U  (all 16 waves; U in registers) --------
    {
      float s = 0.f;
#pragma unroll
      for (int i4 = 0; i4 < 16; ++i4) {
        const float4 pv = *(const float4*)&sh_prev[kq * 64 + i4 * 4];
        s = fmaf(pv.x, ureg[i4 * 4 + 0], s);
        s = fmaf(pv.y, ureg[i4 * 4 + 1], s);
        s = fmaf(pv.z, ureg[i4 * 4 + 2], s);
        s = fmaf(pv.w, ureg[i4 * 4 + 3], s);
      }
      sh_pB[kq][j] = s;
    }
    bar_lds();

    // -------- P5: gates (waves 0-3) + prefetch writeback (waves 4-7) --------
    if (w < 4) {
      const float h2h = (sh_pB[0][j] + sh_pB[1][j]) + (sh_pB[2][j] + sh_pB[3][j]);
      const float xpv = sh_xp[buf][j];
      const float bb = sh_b[j];
      const float s1 = xpv + h2h + bb;
      const float rg = 1.f / (1.f + __expf(-s1));
      const float targ = xpv + rg * h2h + bb;
      const float e2 = __expf(2.f * targ);
      const float ht = 1.f - 2.f / (e2 + 1.f);  // tanh(targ)
      const float pv = sh_prev[j];
      const float hn = (1.f - rg) * pv + rg * ht;
      sh_hnew[j] = hn;
      const float ho = (1.f - mcur) * sh_h[j] + mcur * hn;
      sh_h[j] = ho;
      outs[bt * OUT_ + j] = ho;
    } else if (w == 4) {
      if (hasnext) *(float4*)&sh_x[nbuf][lane * 4] = xpref;
    } else if (w == 5) {
      if (hasnext) *(float4*)&sh_xp[nbuf][lane * 4] = xppref;
    } else if (w == 6) {
      if (hasnext) {
        sh_ri[nbuf][lane] = ripref;
        sh_ro[nbuf][lane] = ropref;
      }
    } else if (w == 7) {
      if (hasnext) {
        sh_ei[nbuf][lane] = eipref;
        sh_eo[nbuf][lane] = eopref;
      }
    }
    bar_lds();

    // -------- P6: memory update + mems output (all 16 waves) --------
    {
      const int c = tid >> 4, d4 = tid & 15;
      const float er = mcur * (float)sh_eo[buf][c];
      const int roc = sh_ro[buf][c];
      const float4 hn4 = *(const float4*)&sh_hnew[roc * 64 + d4 * 4];
      const float4 mp4 = *(const float4*)&sh_m[c][d4 * 4];
      float4 mo;
      mo.x = (1.f - er) * mp4.x + er * hn4.x;
      mo.y = (1.f - er) * mp4.y + er * hn4.y;
      mo.z = (1.f - er) * mp4.z + er * hn4.z;
      mo.w = (1.f - er) * mp4.w + er * hn4.w;
      *(float4*)&sh_m[c][d4 * 4] = mo;
      *(float4*)&mems[(bt * C_ + c) * RD_ + d4 * 4] = mo;
    }
    if (hasnext) mcur = mnext;
    bar_lds();
  }
}

// ---------------------------------------------------------------------------
extern "C" void kernel_launch(void* const* d_in, const int* in_sizes, int n_in,
                              void* d_out, int out_size, void* d_ws, size_t ws_size,
                              hipStream_t stream) {
  const float* X = (const float*)d_in[0];
  const int* M = (const int*)d_in[1];
  const int* Ei = (const int*)d_in[2];
  const int* Eo = (const int*)d_in[3];
  const int* Ri = (const int*)d_in[4];
  const int* Ro = (const int*)d_in[5];
  const float* W = (const float*)d_in[6];
  const float* U = (const float*)d_in[7];
  const float* Bv = (const float*)d_in[8];
  const float* Watt = (const float*)d_in[9];

  float* outs = (float*)d_out;
  float* mems = outs + (size_t)B_ * T_ * OUT_;
  float* aggs = mems + (size_t)B_ * T_ * C_ * RD_;
  float* XP = (float*)d_ws;  // 16384*256 f32 = 16.8 MB

  xpre_kernel<<<dim3(B_ * T_ / 32), dim3(256), 0, stream>>>(X, W, XP);
  gru_kernel<<<dim3(B_), dim3(1024), 0, stream>>>(X, M, Ei, Eo, Ri, Ro, U, Bv,
                                                  Watt, XP, outs, mems, aggs);
}

// Round 3
// 2492.282 us; speedup vs baseline: 1.0298x; 1.0298x over previous
//
#include <hip/hip_runtime.h>

#define B_   32
#define T_   512
#define D_   256
#define C_   64
#define R_   4
#define RD_  64
#define OUT_ 256
#define MSTRIDE 68   // padded row stride for sh_m (16B-aligned, breaks pow2 banks)

// ---------------------------------------------------------------------------
// lgkm-only barrier: publishes LDS writes without draining vmcnt (keeps the
// global prefetch loads in flight across phase barriers). All inter-wave
// communication in this kernel goes through LDS, so lgkmcnt(0)+s_barrier is
// sufficient; register-carried global loads are ordered by compiler-tracked
// register dependencies (vmcnt waits at use).
__device__ __forceinline__ void bar_lds() {
  asm volatile("s_waitcnt lgkmcnt(0)" ::: "memory");
  __builtin_amdgcn_s_barrier();
  asm volatile("" ::: "memory");
}

__device__ __forceinline__ float wave_sum(float v) {
  v += __shfl_xor(v, 1);
  v += __shfl_xor(v, 2);
  v += __shfl_xor(v, 4);
  v += __shfl_xor(v, 8);
  v += __shfl_xor(v, 16);
  v += __shfl_xor(v, 32);
  return v;
}

// ---------------------------------------------------------------------------
// Xpre = X @ W   (16384 x 256) @ (256 x 256), f32
__global__ __launch_bounds__(256) void xpre_kernel(const float* __restrict__ X,
                                                   const float* __restrict__ W,
                                                   float* __restrict__ XP) {
  __shared__ __align__(16) float xs[32][D_];
  const int j = threadIdx.x;
  const int row0 = blockIdx.x * 32;
  for (int k = 0; k < 32; ++k)
    xs[k][j] = X[(size_t)(row0 + k) * D_ + j];
  __syncthreads();
  float acc[32];
#pragma unroll
  for (int k = 0; k < 32; ++k) acc[k] = 0.f;
  for (int d4 = 0; d4 < D_ / 4; ++d4) {
    const float w0 = W[(d4 * 4 + 0) * OUT_ + j];
    const float w1 = W[(d4 * 4 + 1) * OUT_ + j];
    const float w2 = W[(d4 * 4 + 2) * OUT_ + j];
    const float w3 = W[(d4 * 4 + 3) * OUT_ + j];
#pragma unroll
    for (int k = 0; k < 32; ++k) {
      const float4 x4 = *(const float4*)&xs[k][d4 * 4];
      acc[k] = fmaf(x4.x, w0, fmaf(x4.y, w1, fmaf(x4.z, w2, fmaf(x4.w, w3, acc[k]))));
    }
  }
  for (int k = 0; k < 32; ++k)
    XP[(size_t)(row0 + k) * OUT_ + j] = acc[k];
}

// ---------------------------------------------------------------------------
// Main recurrent kernel: one block per batch element, 1024 threads.
// __launch_bounds__(1024, 4): 4 waves/SIMD = exactly 1 workgroup/CU ->
// 128-VGPR budget so ureg[64] (the U slice) stays register-resident.
// There are only 32 blocks on 256 CUs, so 1 wg/CU costs nothing.
__global__ __launch_bounds__(1024, 4) void gru_kernel(
    const float* __restrict__ X, const int* __restrict__ M,
    const int* __restrict__ Ei, const int* __restrict__ Eo,
    const int* __restrict__ Ri, const int* __restrict__ Ro,
    const float* __restrict__ U, const float* __restrict__ Bv,
    const float* __restrict__ Watt, const float* __restrict__ XP,
    float* __restrict__ outs, float* __restrict__ mems,
    float* __restrict__ aggs) {
  __shared__ __align__(16) float sh_x[2][D_];
  __shared__ __align__(16) float sh_xp[2][OUT_];
  __shared__ int sh_ri[2][C_];
  __shared__ int sh_ro[2][C_];
  __shared__ int sh_ei[2][C_];
  __shared__ int sh_eo[2][C_];
  __shared__ __align__(16) float sh_watt[R_][D_];
  __shared__ __align__(16) float sh_b[OUT_];
  __shared__ __align__(16) float sh_h[OUT_];
  __shared__ __align__(16) float sh_m[C_][MSTRIDE];
  __shared__ __align__(16) float sh_wal[R_][C_];   // (ri[c]==r ? alpha[c] : 0)
  __shared__ __align__(16) float sh_prev[OUT_];
  __shared__ __align__(16) float sh_hnew[OUT_];
  __shared__ __align__(16) float sh_pB[4][OUT_];

  const int tid = threadIdx.x;
  const int lane = tid & 63;
  const int w = tid >> 6;
  const int j = tid & 255;
  const int kq = tid >> 8;
  const int b = blockIdx.x;
  const size_t bt0 = (size_t)b * T_;

  // U chunk into registers: ureg[i] = U[kq*64+i][j]
  float ureg[64];
#pragma unroll
  for (int i = 0; i < 64; ++i)
    ureg[i] = U[(size_t)((kq << 6) + i) * OUT_ + j];

  // static LDS
  ((float*)sh_watt)[tid] = Watt[tid];
  if (tid < OUT_) {
    sh_b[tid] = Bv[tid];
    sh_h[tid] = 0.f;
  }
  for (int idx = tid; idx < C_ * RD_; idx += 1024)
    sh_m[idx >> 6][idx & 63] = 0.f;
  // t = 0 inputs
  {
    const size_t bt = bt0;
    if (tid < D_) sh_x[0][tid] = X[bt * D_ + tid];
    else if (tid < 2 * D_) sh_xp[0][tid - D_] = XP[bt * OUT_ + (tid - D_)];
    else if (tid < 2 * D_ + C_) sh_ri[0][tid - 2 * D_] = Ri[bt * C_ + (tid - 2 * D_)];
    else if (tid < 2 * D_ + 2 * C_) sh_ro[0][tid - (2 * D_ + C_)] = Ro[bt * C_ + (tid - (2 * D_ + C_))];
    else if (tid < 2 * D_ + 3 * C_) sh_ei[0][tid - (2 * D_ + 2 * C_)] = Ei[bt * C_ + (tid - (2 * D_ + 2 * C_))];
    else if (tid < 2 * D_ + 4 * C_) sh_eo[0][tid - (2 * D_ + 3 * C_)] = Eo[bt * C_ + (tid - (2 * D_ + 3 * C_))];
  }
  float mcur = (float)M[bt0];
  float mnext = 0.f;
  __syncthreads();

  float4 xpref = {0.f, 0.f, 0.f, 0.f};
  float4 xppref = {0.f, 0.f, 0.f, 0.f};
  int ripref = 0, ropref = 0, eipref = 0, eopref = 0;

  for (int t = 0; t < T_; ++t) {
    const int buf = t & 1, nbuf = buf ^ 1;
    const size_t bt = bt0 + t;
    const bool hasnext = (t + 1 < T_);

    // -------- Phase A: attention (wave 0) | prefetch issue (waves 4-7) -----
    if (w == 0) {
      const float4 x4 = *(const float4*)&sh_x[buf][lane * 4];
      const float4 w0 = *(const float4*)&sh_watt[0][lane * 4];
      const float4 w1 = *(const float4*)&sh_watt[1][lane * 4];
      const float4 w2 = *(const float4*)&sh_watt[2][lane * 4];
      const float4 w3 = *(const float4*)&sh_watt[3][lane * 4];
      float y0 = fmaf(x4.x, w0.x, fmaf(x4.y, w0.y, fmaf(x4.z, w0.z, x4.w * w0.w)));
      float y1 = fmaf(x4.x, w1.x, fmaf(x4.y, w1.y, fmaf(x4.z, w1.z, x4.w * w1.w)));
      float y2 = fmaf(x4.x, w2.x, fmaf(x4.y, w2.y, fmaf(x4.z, w2.z, x4.w * w2.w)));
      float y3 = fmaf(x4.x, w3.x, fmaf(x4.y, w3.y, fmaf(x4.z, w3.z, x4.w * w3.w)));
      y0 = wave_sum(y0);
      y1 = wave_sum(y1);
      y2 = wave_sum(y2);
      y3 = wave_sum(y3);
      const int ric = sh_ri[buf][lane];
      const float eic = (float)sh_ei[buf][lane];
      float yv = (ric & 1) ? y1 : y0;
      const float yw = (ric & 1) ? y3 : y2;
      yv = (ric & 2) ? yw : yv;
      const float am = __expf(yv) * eic;  // EPS=1e-100 underflows to 0 in f32
      const float tot = wave_sum(am);
      const float alpha = am / tot;
      sh_wal[0][lane] = (ric == 0) ? alpha : 0.f;
      sh_wal[1][lane] = (ric == 1) ? alpha : 0.f;
      sh_wal[2][lane] = (ric == 2) ? alpha : 0.f;
      sh_wal[3][lane] = (ric == 3) ? alpha : 0.f;
    } else if (w == 4) {
      if (hasnext) xpref = *(const float4*)&X[(bt + 1) * D_ + lane * 4];
    } else if (w == 5) {
      if (hasnext) xppref = *(const float4*)&XP[(bt + 1) * OUT_ + lane * 4];
    } else if (w == 6) {
      if (hasnext) {
        ripref = Ri[(bt + 1) * C_ + lane];
        ropref = Ro[(bt + 1) * C_ + lane];
      }
    } else if (w == 7) {
      if (hasnext) {
        eipref = Ei[(bt + 1) * C_ + lane];
        eopref = Eo[(bt + 1) * C_ + lane];
      }
    }
    if (hasnext) mnext = (float)M[bt + 1];
    bar_lds();

    // -------- Phase B: prev (waves 0-3: r = w, d = lane) | aggs (wave 4) ----
    if (w < 4) {
      const int d = lane;
      float a0 = 0.f, a1 = 0.f, a2 = 0.f, a3 = 0.f;
#pragma unroll
      for (int c4 = 0; c4 < 16; ++c4) {
        const float4 wv = *(const float4*)&sh_wal[w][c4 * 4];  // broadcast
        a0 = fmaf(wv.x, sh_m[c4 * 4 + 0][d], a0);
        a1 = fmaf(wv.y, sh_m[c4 * 4 + 1][d], a1);
        a2 = fmaf(wv.z, sh_m[c4 * 4 + 2][d], a2);
        a3 = fmaf(wv.w, sh_m[c4 * 4 + 3][d], a3);
      }
      sh_prev[(w << 6) + d] = (a0 + a1) + (a2 + a3);
    } else if (w == 4) {
      float s0 = sh_wal[0][lane];
      float s1 = sh_wal[1][lane];
      float s2 = sh_wal[2][lane];
      float s3 = sh_wal[3][lane];
      s0 = wave_sum(s0);
      s1 = wave_sum(s1);
      s2 = wave_sum(s2);
      s3 = wave_sum(s3);
      if (lane == 0) {
        float4 v = {s0, s1, s2, s3};
        *(float4*)&aggs[bt * R_] = v;
      }
    }
    bar_lds();

    // -------- Phase C: h2h = prev @ U  (all 16 waves; U in registers) -------
    {
      float s0 = 0.f, s1 = 0.f;
#pragma unroll
      for (int i4 = 0; i4 < 16; ++i4) {
        const float4 pv = *(const float4*)&sh_prev[(kq << 6) + i4 * 4];
        if (i4 & 1) {
          s1 = fmaf(pv.x, ureg[i4 * 4 + 0], s1);
          s1 = fmaf(pv.y, ureg[i4 * 4 + 1], s1);
          s1 = fmaf(pv.z, ureg[i4 * 4 + 2], s1);
          s1 = fmaf(pv.w, ureg[i4 * 4 + 3], s1);
        } else {
          s0 = fmaf(pv.x, ureg[i4 * 4 + 0], s0);
          s0 = fmaf(pv.y, ureg[i4 * 4 + 1], s0);
          s0 = fmaf(pv.z, ureg[i4 * 4 + 2], s0);
          s0 = fmaf(pv.w, ureg[i4 * 4 + 3], s0);
        }
      }
      sh_pB[kq][j] = s0 + s1;
    }
    bar_lds();

    // -------- Phase D: gates (waves 0-3) | prefetch writeback (waves 4-7) ---
    if (w < 4) {
      const float h2h = (sh_pB[0][j] + sh_pB[1][j]) + (sh_pB[2][j] + sh_pB[3][j]);
      const float xpv = sh_xp[buf][j];
      const float bb = sh_b[j];
      const float s1 = xpv + h2h + bb;
      const float rg = 1.f / (1.f + __expf(-s1));
      const float targ = xpv + rg * h2h + bb;
      const float e2 = __expf(2.f * targ);
      const float ht = 1.f - 2.f / (e2 + 1.f);  // tanh(targ)
      const float pv = sh_prev[j];
      const float hn = (1.f - rg) * pv + rg * ht;
      sh_hnew[j] = hn;
      const float ho = (mcur != 0.f) ? hn : sh_h[j];  // mcur is exactly 0/1
      sh_h[j] = ho;
      outs[bt * OUT_ + j] = ho;
    } else if (w == 4) {
      if (hasnext) *(float4*)&sh_x[nbuf][lane * 4] = xpref;
    } else if (w == 5) {
      if (hasnext) *(float4*)&sh_xp[nbuf][lane * 4] = xppref;
    } else if (w == 6) {
      if (hasnext) {
        sh_ri[nbuf][lane] = ripref;
        sh_ro[nbuf][lane] = ropref;
      }
    } else if (w == 7) {
      if (hasnext) {
        sh_ei[nbuf][lane] = eipref;
        sh_eo[nbuf][lane] = eopref;
      }
    }
    bar_lds();

    // -------- Phase E: memory update + mems output (all 16 waves) ----------
    // Dedicated barrier-bracketed phase (round-1-validated structure; the
    // concurrent-with-Phase-A variant failed post-timing revalidation).
    {
      const int c = tid >> 4, d4 = tid & 15;
      const float er = mcur * (float)sh_eo[buf][c];  // exactly 0 or 1
      const int roc = sh_ro[buf][c];
      const float4 hn4 = *(const float4*)&sh_hnew[(roc << 6) + d4 * 4];
      const float4 mp4 = *(const float4*)&sh_m[c][d4 * 4];
      const bool e = (er != 0.f);
      float4 mo;
      mo.x = e ? hn4.x : mp4.x;
      mo.y = e ? hn4.y : mp4.y;
      mo.z = e ? hn4.z : mp4.z;
      mo.w = e ? hn4.w : mp4.w;
      *(float4*)&sh_m[c][d4 * 4] = mo;
      *(float4*)&mems[(bt * C_ + c) * RD_ + d4 * 4] = mo;
    }
    if (hasnext) mcur = mnext;
    bar_lds();
  }
}

// ---------------------------------------------------------------------------
extern "C" void kernel_launch(void* const* d_in, const int* in_sizes, int n_in,
                              void* d_out, int out_size, void* d_ws, size_t ws_size,
                              hipStream_t stream) {
  const float* X = (const float*)d_in[0];
  const int* M = (const int*)d_in[1];
  const int* Ei = (const int*)d_in[2];
  const int* Eo = (const int*)d_in[3];
  const int* Ri = (const int*)d_in[4];
  const int* Ro = (const int*)d_in[5];
  const float* W = (const float*)d_in[6];
  const float* U = (const float*)d_in[7];
  const float* Bv = (const float*)d_in[8];
  const float* Watt = (const float*)d_in[9];

  float* outs = (float*)d_out;
  float* mems = outs + (size_t)B_ * T_ * OUT_;
  float* aggs = mems + (size_t)B_ * T_ * C_ * RD_;
  float* XP = (float*)d_ws;  // 16384*256 f32 = 16.8 MB

  xpre_kernel<<<dim3(B_ * T_ / 32), dim3(256), 0, stream>>>(X, W, XP);
  gru_kernel<<<dim3(B_), dim3(1024), 0, stream>>>(X, M, Ei, Eo, Ri, Ro, U, Bv,
                                                  Watt, XP, outs, mems, aggs);
}

// Round 4
// 2332.703 us; speedup vs baseline: 1.1003x; 1.0684x over previous
//
#include <hip/hip_runtime.h>

#define B_   32
#define T_   512
#define D_   256
#define C_   64
#define R_   4
#define RD_  64
#define OUT_ 256

// ---------------------------------------------------------------------------
// lgkm-only barrier: publishes LDS writes without draining vmcnt (keeps the
// global prefetch loads in flight across phase barriers).
__device__ __forceinline__ void bar_lds() {
  asm volatile("s_waitcnt lgkmcnt(0)" ::: "memory");
  __builtin_amdgcn_s_barrier();
  asm volatile("" ::: "memory");
}

__device__ __forceinline__ float wave_sum(float v) {
  v += __shfl_xor(v, 1);
  v += __shfl_xor(v, 2);
  v += __shfl_xor(v, 4);
  v += __shfl_xor(v, 8);
  v += __shfl_xor(v, 16);
  v += __shfl_xor(v, 32);
  return v;
}

// ---------------------------------------------------------------------------
// Xpre = X @ W   (16384 x 256) @ (256 x 256), f32
__global__ __launch_bounds__(256) void xpre_kernel(const float* __restrict__ X,
                                                   const float* __restrict__ W,
                                                   float* __restrict__ XP) {
  __shared__ __align__(16) float xs[32][D_];
  const int j = threadIdx.x;
  const int row0 = blockIdx.x * 32;
  for (int k = 0; k < 32; ++k)
    xs[k][j] = X[(size_t)(row0 + k) * D_ + j];
  __syncthreads();
  float acc[32];
#pragma unroll
  for (int k = 0; k < 32; ++k) acc[k] = 0.f;
  for (int d4 = 0; d4 < D_ / 4; ++d4) {
    const float w0 = W[(d4 * 4 + 0) * OUT_ + j];
    const float w1 = W[(d4 * 4 + 1) * OUT_ + j];
    const float w2 = W[(d4 * 4 + 2) * OUT_ + j];
    const float w3 = W[(d4 * 4 + 3) * OUT_ + j];
#pragma unroll
    for (int k = 0; k < 32; ++k) {
      const float4 x4 = *(const float4*)&xs[k][d4 * 4];
      acc[k] = fmaf(x4.x, w0, fmaf(x4.y, w1, fmaf(x4.z, w2, fmaf(x4.w, w3, acc[k]))));
    }
  }
  for (int k = 0; k < 32; ++k)
    XP[(size_t)(row0 + k) * OUT_ + j] = acc[k];
}

// ---------------------------------------------------------------------------
// Main recurrent kernel: one block (16 waves) per batch element.
// m is stored TRANSPOSED + XOR-swizzled in LDS: element (d, c) lives at word
//   d*64 + (c ^ ((d&7)<<2))
// so both the prev-GEMV (read cols c-blocks for fixed d) and the m-update
// (write c-blocks for fixed d) are conflict-free ds_*_b128.
__global__ __launch_bounds__(1024, 4) void gru_kernel(
    const float* __restrict__ X, const int* __restrict__ M,
    const int* __restrict__ Ei, const int* __restrict__ Eo,
    const int* __restrict__ Ri, const int* __restrict__ Ro,
    const float* __restrict__ U, const float* __restrict__ Bv,
    const float* __restrict__ Watt, const float* __restrict__ XP,
    float* __restrict__ outs, float* __restrict__ mems,
    float* __restrict__ aggs) {
  __shared__ __align__(16) float sh_x[2][D_];
  __shared__ __align__(16) float sh_xp[2][OUT_];
  __shared__ int sh_ri[2][C_];
  __shared__ int sh_ro[2][C_];
  __shared__ int sh_ei[2][C_];
  __shared__ int sh_eo[2][C_];
  __shared__ __align__(16) float sh_watt[R_][D_];
  __shared__ __align__(16) float sh_mt[C_ * RD_];  // transposed+swizzled m
  __shared__ __align__(16) float sh_wal[R_][C_];   // (ri[c]==r ? alpha[c] : 0)
  __shared__ __align__(16) float sh_prev[OUT_];
  __shared__ __align__(16) float sh_hnew[OUT_];
  __shared__ __align__(16) float sh_pB[4][OUT_];

  const int tid = threadIdx.x;
  const int lane = tid & 63;
  const int w = tid >> 6;
  const int j = tid & 255;
  const int kq = tid >> 8;
  const int b = blockIdx.x;
  const size_t bt0 = (size_t)b * T_;

  // U chunk: ureg[i] = U[kq*64+i][j]  (lives in AGPRs; arch+acc = 128 budget)
  float ureg[64];
#pragma unroll
  for (int i = 0; i < 64; ++i)
    ureg[i] = U[(size_t)((kq << 6) + i) * OUT_ + j];

  float hreg = 0.f;                       // h state, only meaningful for w<4
  float breg = (tid < OUT_) ? Bv[tid] : 0.f;

  // static LDS init
  ((float*)sh_watt)[tid] = Watt[tid];
  for (int idx = tid; idx < C_ * RD_; idx += 1024) sh_mt[idx] = 0.f;
  // t = 0 inputs
  {
    const size_t bt = bt0;
    if (tid < D_) sh_x[0][tid] = X[bt * D_ + tid];
    else if (tid < 2 * D_) sh_xp[0][tid - D_] = XP[bt * OUT_ + (tid - D_)];
    else if (tid < 2 * D_ + C_) sh_ri[0][tid - 2 * D_] = Ri[bt * C_ + (tid - 2 * D_)];
    else if (tid < 2 * D_ + 2 * C_) sh_ro[0][tid - (2 * D_ + C_)] = Ro[bt * C_ + (tid - (2 * D_ + C_))];
    else if (tid < 2 * D_ + 3 * C_) sh_ei[0][tid - (2 * D_ + 2 * C_)] = Ei[bt * C_ + (tid - (2 * D_ + 2 * C_))];
    else if (tid < 2 * D_ + 4 * C_) sh_eo[0][tid - (2 * D_ + 3 * C_)] = Eo[bt * C_ + (tid - (2 * D_ + 3 * C_))];
  }
  float mcur = (float)M[bt0];
  float mnext = 0.f;

  // attention for step buffer pbuf (wave 0 only): alpha -> sh_wal
  auto attention = [&](int pbuf) {
    const float4 x4 = *(const float4*)&sh_x[pbuf][lane * 4];
    const float4 w0 = *(const float4*)&sh_watt[0][lane * 4];
    const float4 w1 = *(const float4*)&sh_watt[1][lane * 4];
    const float4 w2 = *(const float4*)&sh_watt[2][lane * 4];
    const float4 w3 = *(const float4*)&sh_watt[3][lane * 4];
    float y0 = fmaf(x4.x, w0.x, fmaf(x4.y, w0.y, fmaf(x4.z, w0.z, x4.w * w0.w)));
    float y1 = fmaf(x4.x, w1.x, fmaf(x4.y, w1.y, fmaf(x4.z, w1.z, x4.w * w1.w)));
    float y2 = fmaf(x4.x, w2.x, fmaf(x4.y, w2.y, fmaf(x4.z, w2.z, x4.w * w2.w)));
    float y3 = fmaf(x4.x, w3.x, fmaf(x4.y, w3.y, fmaf(x4.z, w3.z, x4.w * w3.w)));
    y0 = wave_sum(y0);
    y1 = wave_sum(y1);
    y2 = wave_sum(y2);
    y3 = wave_sum(y3);
    const int ric = sh_ri[pbuf][lane];
    const float eic = (float)sh_ei[pbuf][lane];
    float yv = (ric & 1) ? y1 : y0;
    const float yw = (ric & 1) ? y3 : y2;
    yv = (ric & 2) ? yw : yv;
    const float am = __expf(yv) * eic;  // EPS=1e-100 underflows to 0 in f32
    const float tot = wave_sum(am);
    const float alpha = am / tot;
    sh_wal[0][lane] = (ric == 0) ? alpha : 0.f;
    sh_wal[1][lane] = (ric == 1) ? alpha : 0.f;
    sh_wal[2][lane] = (ric == 2) ? alpha : 0.f;
    sh_wal[3][lane] = (ric == 3) ? alpha : 0.f;
  };

  __syncthreads();
  if (w == 0) attention(0);  // prologue: alpha for t=0
  bar_lds();

  float4 xpref = {0.f, 0.f, 0.f, 0.f};
  float4 xppref = {0.f, 0.f, 0.f, 0.f};
  int ripref = 0, ropref = 0, eipref = 0, eopref = 0;

  for (int t = 0; t < T_; ++t) {
    const int buf = t & 1, nbuf = buf ^ 1;
    const size_t bt = bt0 + t;
    const bool hasnext = (t + 1 < T_);
    float prevreg = 0.f;

    // ---- Phase B: prev (w0-3) | aggs (w4) | prefetch issue (w5-8) ----------
    if (w < 4) {
      const int d = lane;
      const int s = (d & 7) << 2;
      const int mbase = d << 6;
      float a0 = 0.f, a1 = 0.f, a2 = 0.f, a3 = 0.f;
#pragma unroll
      for (int c4 = 0; c4 < 16; ++c4) {
        const int c0 = c4 << 2;
        const float4 mv = *(const float4*)&sh_mt[mbase + (c0 ^ s)];
        const float4 wv = *(const float4*)&sh_wal[w][c0];  // broadcast
        a0 = fmaf(wv.x, mv.x, a0);
        a1 = fmaf(wv.y, mv.y, a1);
        a2 = fmaf(wv.z, mv.z, a2);
        a3 = fmaf(wv.w, mv.w, a3);
      }
      prevreg = (a0 + a1) + (a2 + a3);
      sh_prev[(w << 6) + d] = prevreg;
    } else if (w == 4) {
      float s0 = sh_wal[0][lane];
      float s1 = sh_wal[1][lane];
      float s2 = sh_wal[2][lane];
      float s3 = sh_wal[3][lane];
      s0 = wave_sum(s0);
      s1 = wave_sum(s1);
      s2 = wave_sum(s2);
      s3 = wave_sum(s3);
      if (lane == 0) {
        float4 v = {s0, s1, s2, s3};
        *(float4*)&aggs[bt * R_] = v;
      }
    } else if (w == 5) {
      if (hasnext) xpref = *(const float4*)&X[(bt + 1) * D_ + lane * 4];
    } else if (w == 6) {
      if (hasnext) xppref = *(const float4*)&XP[(bt + 1) * OUT_ + lane * 4];
    } else if (w == 7) {
      if (hasnext) {
        ripref = Ri[(bt + 1) * C_ + lane];
        ropref = Ro[(bt + 1) * C_ + lane];
      }
    } else if (w == 8) {
      if (hasnext) {
        eipref = Ei[(bt + 1) * C_ + lane];
        eopref = Eo[(bt + 1) * C_ + lane];
      }
    }
    if (hasnext) mnext = (float)M[bt + 1];
    bar_lds();

    // ---- Phase C: h2h partials = prev @ U (all 16 waves, U in AGPRs) -------
    {
      float s0 = 0.f, s1 = 0.f;
#pragma unroll
      for (int i4 = 0; i4 < 16; ++i4) {
        const float4 pv = *(const float4*)&sh_prev[(kq << 6) + i4 * 4];  // bcast
        if (i4 & 1) {
          s1 = fmaf(pv.x, ureg[i4 * 4 + 0], s1);
          s1 = fmaf(pv.y, ureg[i4 * 4 + 1], s1);
          s1 = fmaf(pv.z, ureg[i4 * 4 + 2], s1);
          s1 = fmaf(pv.w, ureg[i4 * 4 + 3], s1);
        } else {
          s0 = fmaf(pv.x, ureg[i4 * 4 + 0], s0);
          s0 = fmaf(pv.y, ureg[i4 * 4 + 1], s0);
          s0 = fmaf(pv.z, ureg[i4 * 4 + 2], s0);
          s0 = fmaf(pv.w, ureg[i4 * 4 + 3], s0);
        }
      }
      sh_pB[kq][j] = s0 + s1;
    }
    bar_lds();

    // ---- Phase D: gates+outs (w0-3) | prefetch writeback (w5-8) ------------
    if (w < 4) {
      const float h2h = (sh_pB[0][j] + sh_pB[1][j]) + (sh_pB[2][j] + sh_pB[3][j]);
      const float xpv = sh_xp[buf][j];
      const float s1 = xpv + h2h + breg;
      const float rg = 1.f / (1.f + __expf(-s1));
      const float targ = xpv + rg * h2h + breg;
      const float e2 = __expf(2.f * targ);
      const float ht = 1.f - 2.f / (e2 + 1.f);  // tanh(targ)
      const float hn = (1.f - rg) * prevreg + rg * ht;
      sh_hnew[j] = hn;
      hreg = (mcur != 0.f) ? hn : hreg;  // mcur is exactly 0/1
      outs[bt * OUT_ + j] = hreg;
    } else if (w == 5) {
      if (hasnext) *(float4*)&sh_x[nbuf][lane * 4] = xpref;
    } else if (w == 6) {
      if (hasnext) *(float4*)&sh_xp[nbuf][lane * 4] = xppref;
    } else if (w == 7) {
      if (hasnext) {
        sh_ri[nbuf][lane] = ripref;
        sh_ro[nbuf][lane] = ropref;
      }
    } else if (w == 8) {
      if (hasnext) {
        sh_ei[nbuf][lane] = eipref;
        sh_eo[nbuf][lane] = eopref;
      }
    }
    bar_lds();

    // ---- Phase E: m-update+mems (w8-15) | attention(t+1) (w0) --------------
    // Disjoint LDS sets: w0 reads sh_x/ri/ei[nbuf] (written D(t)), writes
    // sh_wal (read next B); w8-15 touch sh_mt/sh_hnew/sh_ro/sh_eo[buf]/mems.
    if (w == 0) {
      if (hasnext) attention(nbuf);
    } else if (w >= 8) {
      const int idx = tid - 512;     // 0..511
      const int d = idx & 63;
      const int c8 = idx >> 6;       // 0..7, wave-uniform
      const int s = (d & 7) << 2;
      const int mbase = d << 6;
      const int c0a = c8 << 3;
      const int c0b = c0a + 4;
      float4 ma = *(float4*)&sh_mt[mbase + (c0a ^ s)];
      float4 mb = *(float4*)&sh_mt[mbase + (c0b ^ s)];
      // c0a block
      {
        const float e0 = mcur * (float)sh_eo[buf][c0a + 0];
        const float e1 = mcur * (float)sh_eo[buf][c0a + 1];
        const float e2_ = mcur * (float)sh_eo[buf][c0a + 2];
        const float e3 = mcur * (float)sh_eo[buf][c0a + 3];
        const float h0 = sh_hnew[(sh_ro[buf][c0a + 0] << 6) + d];
        const float h1 = sh_hnew[(sh_ro[buf][c0a + 1] << 6) + d];
        const float h2 = sh_hnew[(sh_ro[buf][c0a + 2] << 6) + d];
        const float h3 = sh_hnew[(sh_ro[buf][c0a + 3] << 6) + d];
        ma.x = (e0 != 0.f) ? h0 : ma.x;
        ma.y = (e1 != 0.f) ? h1 : ma.y;
        ma.z = (e2_ != 0.f) ? h2 : ma.z;
        ma.w = (e3 != 0.f) ? h3 : ma.w;
      }
      // c0b block
      {
        const float e0 = mcur * (float)sh_eo[buf][c0b + 0];
        const float e1 = mcur * (float)sh_eo[buf][c0b + 1];
        const float e2_ = mcur * (float)sh_eo[buf][c0b + 2];
        const float e3 = mcur * (float)sh_eo[buf][c0b + 3];
        const float h0 = sh_hnew[(sh_ro[buf][c0b + 0] << 6) + d];
        const float h1 = sh_hnew[(sh_ro[buf][c0b + 1] << 6) + d];
        const float h2 = sh_hnew[(sh_ro[buf][c0b + 2] << 6) + d];
        const float h3 = sh_hnew[(sh_ro[buf][c0b + 3] << 6) + d];
        mb.x = (e0 != 0.f) ? h0 : mb.x;
        mb.y = (e1 != 0.f) ? h1 : mb.y;
        mb.z = (e2_ != 0.f) ? h2 : mb.z;
        mb.w = (e3 != 0.f) ? h3 : mb.w;
      }
      *(float4*)&sh_mt[mbase + (c0a ^ s)] = ma;
      *(float4*)&sh_mt[mbase + (c0b ^ s)] = mb;
      const size_t mbg = (bt * C_) * RD_ + d;
      mems[mbg + (size_t)(c0a + 0) * RD_] = ma.x;
      mems[mbg + (size_t)(c0a + 1) * RD_] = ma.y;
      mems[mbg + (size_t)(c0a + 2) * RD_] = ma.z;
      mems[mbg + (size_t)(c0a + 3) * RD_] = ma.w;
      mems[mbg + (size_t)(c0b + 0) * RD_] = mb.x;
      mems[mbg + (size_t)(c0b + 1) * RD_] = mb.y;
      mems[mbg + (size_t)(c0b + 2) * RD_] = mb.z;
      mems[mbg + (size_t)(c0b + 3) * RD_] = mb.w;
    }
    bar_lds();

    if (hasnext) mcur = mnext;
  }
}

// ---------------------------------------------------------------------------
extern "C" void kernel_launch(void* const* d_in, const int* in_sizes, int n_in,
                              void* d_out, int out_size, void* d_ws, size_t ws_size,
                              hipStream_t stream) {
  const float* X = (const float*)d_in[0];
  const int* M = (const int*)d_in[1];
  const int* Ei = (const int*)d_in[2];
  const int* Eo = (const int*)d_in[3];
  const int* Ri = (const int*)d_in[4];
  const int* Ro = (const int*)d_in[5];
  const float* W = (const float*)d_in[6];
  const float* U = (const float*)d_in[7];
  const float* Bv = (const float*)d_in[8];
  const float* Watt = (const float*)d_in[9];

  float* outs = (float*)d_out;
  float* mems = outs + (size_t)B_ * T_ * OUT_;
  float* aggs = mems + (size_t)B_ * T_ * C_ * RD_;
  float* XP = (float*)d_ws;  // 16384*256 f32 = 16.8 MB

  xpre_kernel<<<dim3(B_ * T_ / 32), dim3(256), 0, stream>>>(X, W, XP);
  gru_kernel<<<dim3(B_), dim3(1024), 0, stream>>>(X, M, Ei, Eo, Ri, Ro, U, Bv,
                                                  Watt, XP, outs, mems, aggs);
}

// Round 5
// 2189.814 us; speedup vs baseline: 1.1721x; 1.0653x over previous
//
#include <hip/hip_runtime.h>

#define B_   32
#define T_   512
#define D_   256
#define C_   64
#define R_   4
#define RD_  64
#define OUT_ 256

// ---------------------------------------------------------------------------
// lgkm-only barrier: publishes LDS writes without draining vmcnt (keeps the
// global prefetch loads in flight across phase barriers).
__device__ __forceinline__ void bar_lds() {
  asm volatile("s_waitcnt lgkmcnt(0)" ::: "memory");
  __builtin_amdgcn_s_barrier();
  asm volatile("" ::: "memory");
}

__device__ __forceinline__ float wave_sum(float v) {
  v += __shfl_xor(v, 1);
  v += __shfl_xor(v, 2);
  v += __shfl_xor(v, 4);
  v += __shfl_xor(v, 8);
  v += __shfl_xor(v, 16);
  v += __shfl_xor(v, 32);
  return v;
}

// ---------------------------------------------------------------------------
// Xpre = X @ W   (16384 x 256) @ (256 x 256), f32
__global__ __launch_bounds__(256) void xpre_kernel(const float* __restrict__ X,
                                                   const float* __restrict__ W,
                                                   float* __restrict__ XP) {
  __shared__ __align__(16) float xs[32][D_];
  const int j = threadIdx.x;
  const int row0 = blockIdx.x * 32;
  for (int k = 0; k < 32; ++k)
    xs[k][j] = X[(size_t)(row0 + k) * D_ + j];
  __syncthreads();
  float acc[32];
#pragma unroll
  for (int k = 0; k < 32; ++k) acc[k] = 0.f;
  for (int d4 = 0; d4 < D_ / 4; ++d4) {
    const float w0 = W[(d4 * 4 + 0) * OUT_ + j];
    const float w1 = W[(d4 * 4 + 1) * OUT_ + j];
    const float w2 = W[(d4 * 4 + 2) * OUT_ + j];
    const float w3 = W[(d4 * 4 + 3) * OUT_ + j];
#pragma unroll
    for (int k = 0; k < 32; ++k) {
      const float4 x4 = *(const float4*)&xs[k][d4 * 4];
      acc[k] = fmaf(x4.x, w0, fmaf(x4.y, w1, fmaf(x4.z, w2, fmaf(x4.w, w3, acc[k]))));
    }
  }
  for (int k = 0; k < 32; ++k)
    XP[(size_t)(row0 + k) * OUT_ + j] = acc[k];
}

// ---------------------------------------------------------------------------
// Main recurrent kernel: one block (16 waves) per batch element.
// Key insight: M[b,t] in {0,1} is block-uniform per step. When m==0 the whole
// prev -> h2h -> gates -> m-update chain is dead (hout=hprev, mout=mprev);
// the step reduces to {aggs, outs copy, mems copy, prefetch, attention}.
// m is stored TRANSPOSED + XOR-swizzled in LDS: element (d, c) at word
//   d*64 + (c ^ ((d&7)<<2)).
// Attention runs fully in-register on wave 4 (x/ri/ei prefetched to regs).
__global__ __launch_bounds__(1024, 4) void gru_kernel(
    const float* __restrict__ X, const int* __restrict__ M,
    const int* __restrict__ Ei, const int* __restrict__ Eo,
    const int* __restrict__ Ri, const int* __restrict__ Ro,
    const float* __restrict__ U, const float* __restrict__ Bv,
    const float* __restrict__ Watt, const float* __restrict__ XP,
    float* __restrict__ outs, float* __restrict__ mems,
    float* __restrict__ aggs) {
  __shared__ __align__(16) float sh_xp[2][OUT_];
  __shared__ int sh_ro[2][C_];
  __shared__ int sh_eo[2][C_];
  __shared__ __align__(16) float sh_watt[R_][D_];
  __shared__ __align__(16) float sh_mt[C_ * RD_];   // transposed+swizzled m
  __shared__ __align__(16) float sh_wal[2][R_][C_]; // dbuf (ri==r ? alpha : 0)
  __shared__ __align__(16) float sh_prev[OUT_];
  __shared__ __align__(16) float sh_hnew[OUT_];
  __shared__ __align__(16) float sh_pB[4][OUT_];
  __shared__ int sh_M[T_];

  const int tid = threadIdx.x;
  const int lane = tid & 63;
  const int w = tid >> 6;
  const int j = tid & 255;
  const int kq = tid >> 8;
  const int b = blockIdx.x;
  const size_t bt0 = (size_t)b * T_;

  // U chunk: ureg[i] = U[kq*64+i][j]  (AGPR-resident; arch+acc = 64+64)
  float ureg[64];
#pragma unroll
  for (int i = 0; i < 64; ++i)
    ureg[i] = U[(size_t)((kq << 6) + i) * OUT_ + j];

  float hreg = 0.f;                        // h state (meaningful for w<4)
  float breg = (tid < OUT_) ? Bv[tid] : 0.f;

  // static LDS init
  ((float*)sh_watt)[tid] = Watt[tid];
  for (int idx = tid; idx < C_ * RD_; idx += 1024) sh_mt[idx] = 0.f;
  if (tid < T_) sh_M[tid] = M[bt0 + tid];
  if (tid < OUT_) sh_xp[0][tid] = XP[bt0 * OUT_ + tid];
  if (tid >= OUT_ && tid < OUT_ + C_) sh_ro[0][tid - OUT_] = Ro[bt0 * C_ + (tid - OUT_)];
  if (tid >= OUT_ + C_ && tid < OUT_ + 2 * C_)
    sh_eo[0][tid - OUT_ - C_] = Eo[bt0 * C_ + (tid - OUT_ - C_)];
  __syncthreads();

  int mcurI = sh_M[0];

  // attention (wave 4 only, fully in-register inputs): alpha rows -> wal
  auto attention_reg = [&](const float4& x4, int ric, int eic, float (*wal)[C_]) {
    const float4 w0 = *(const float4*)&sh_watt[0][lane * 4];
    const float4 w1 = *(const float4*)&sh_watt[1][lane * 4];
    const float4 w2 = *(const float4*)&sh_watt[2][lane * 4];
    const float4 w3 = *(const float4*)&sh_watt[3][lane * 4];
    float y0 = fmaf(x4.x, w0.x, fmaf(x4.y, w0.y, fmaf(x4.z, w0.z, x4.w * w0.w)));
    float y1 = fmaf(x4.x, w1.x, fmaf(x4.y, w1.y, fmaf(x4.z, w1.z, x4.w * w1.w)));
    float y2 = fmaf(x4.x, w2.x, fmaf(x4.y, w2.y, fmaf(x4.z, w2.z, x4.w * w2.w)));
    float y3 = fmaf(x4.x, w3.x, fmaf(x4.y, w3.y, fmaf(x4.z, w3.z, x4.w * w3.w)));
    y0 = wave_sum(y0);
    y1 = wave_sum(y1);
    y2 = wave_sum(y2);
    y3 = wave_sum(y3);
    float yv = (ric & 1) ? y1 : y0;
    const float yw = (ric & 1) ? y3 : y2;
    yv = (ric & 2) ? yw : yv;
    const float am = __expf(yv) * (float)eic;  // EPS=1e-100 underflows in f32
    const float tot = wave_sum(am);
    const float alpha = am / tot;
    wal[0][lane] = (ric == 0) ? alpha : 0.f;
    wal[1][lane] = (ric == 1) ? alpha : 0.f;
    wal[2][lane] = (ric == 2) ? alpha : 0.f;
    wal[3][lane] = (ric == 3) ? alpha : 0.f;
  };

  // prologue: attention for t=0 from direct global loads (wave 4)
  if (w == 4) {
    const float4 x0 = *(const float4*)&X[bt0 * D_ + lane * 4];
    const int ri0 = Ri[bt0 * C_ + lane];
    const int ei0 = Ei[bt0 * C_ + lane];
    attention_reg(x0, ri0, ei0, sh_wal[0]);
  }
  bar_lds();

  float4 xpref = {0.f, 0.f, 0.f, 0.f};
  float4 xppref = {0.f, 0.f, 0.f, 0.f};
  int ripref = 0, eipref = 0, ropref = 0, eopref = 0;
  int mnextI = 0;

  for (int t = 0; t < T_; ++t) {
    const int buf = t & 1, nbuf = buf ^ 1;
    const size_t bt = bt0 + t;
    const bool hasnext = (t + 1 < T_);

    if (mcurI != 0) {
      // =================== m == 1 : full step (4 barriers) ===================
      float prevreg = 0.f;

      // ---- B: prev (w0-3) | aggs + x/ri/ei issue (w4) | xp,ro/eo issue -----
      if (w < 4) {
        const int d = lane;
        const int s = (d & 7) << 2;
        const int mbase = d << 6;
        float a0 = 0.f, a1 = 0.f, a2 = 0.f, a3 = 0.f;
#pragma unroll
        for (int c4 = 0; c4 < 16; ++c4) {
          const int c0 = c4 << 2;
          const float4 mv = *(const float4*)&sh_mt[mbase + (c0 ^ s)];
          const float4 wv = *(const float4*)&sh_wal[buf][w][c0];  // broadcast
          a0 = fmaf(wv.x, mv.x, a0);
          a1 = fmaf(wv.y, mv.y, a1);
          a2 = fmaf(wv.z, mv.z, a2);
          a3 = fmaf(wv.w, mv.w, a3);
        }
        prevreg = (a0 + a1) + (a2 + a3);
        sh_prev[(w << 6) + d] = prevreg;
      } else if (w == 4) {
        if (hasnext) {
          xpref = *(const float4*)&X[(bt + 1) * D_ + lane * 4];
          ripref = Ri[(bt + 1) * C_ + lane];
          eipref = Ei[(bt + 1) * C_ + lane];
        }
        float s0 = sh_wal[buf][0][lane];
        float s1 = sh_wal[buf][1][lane];
        float s2 = sh_wal[buf][2][lane];
        float s3 = sh_wal[buf][3][lane];
        s0 = wave_sum(s0);
        s1 = wave_sum(s1);
        s2 = wave_sum(s2);
        s3 = wave_sum(s3);
        if (lane == 0) {
          float4 v = {s0, s1, s2, s3};
          *(float4*)&aggs[bt * R_] = v;
        }
      } else if (w == 5) {
        if (hasnext) xppref = *(const float4*)&XP[(bt + 1) * OUT_ + lane * 4];
      } else if (w == 6) {
        if (hasnext) {
          ropref = Ro[(bt + 1) * C_ + lane];
          eopref = Eo[(bt + 1) * C_ + lane];
        }
      }
      mnextI = hasnext ? sh_M[t + 1] : 0;
      bar_lds();

      // ---- C: h2h partials = prev @ U (all 16 waves, U in AGPRs) -----------
      {
        float s0 = 0.f, s1 = 0.f;
#pragma unroll
        for (int i4 = 0; i4 < 16; ++i4) {
          const float4 pv = *(const float4*)&sh_prev[(kq << 6) + i4 * 4];
          if (i4 & 1) {
            s1 = fmaf(pv.x, ureg[i4 * 4 + 0], s1);
            s1 = fmaf(pv.y, ureg[i4 * 4 + 1], s1);
            s1 = fmaf(pv.z, ureg[i4 * 4 + 2], s1);
            s1 = fmaf(pv.w, ureg[i4 * 4 + 3], s1);
          } else {
            s0 = fmaf(pv.x, ureg[i4 * 4 + 0], s0);
            s0 = fmaf(pv.y, ureg[i4 * 4 + 1], s0);
            s0 = fmaf(pv.z, ureg[i4 * 4 + 2], s0);
            s0 = fmaf(pv.w, ureg[i4 * 4 + 3], s0);
          }
        }
        sh_pB[kq][j] = s0 + s1;
      }
      bar_lds();

      // ---- D: gates+outs (w0-3) | attention(t+1) (w4) | writeback (w5,6) ---
      if (w < 4) {
        const float h2h = (sh_pB[0][j] + sh_pB[1][j]) + (sh_pB[2][j] + sh_pB[3][j]);
        const float xpv = sh_xp[buf][j];
        const float s1 = xpv + h2h + breg;
        const float rg = 1.f / (1.f + __expf(-s1));
        const float targ = xpv + rg * h2h + breg;
        const float e2 = __expf(2.f * targ);
        const float ht = 1.f - 2.f / (e2 + 1.f);  // tanh(targ)
        const float hn = (1.f - rg) * prevreg + rg * ht;
        sh_hnew[j] = hn;
        hreg = hn;  // mcur == 1
        outs[bt * OUT_ + j] = hn;
      } else if (w == 4) {
        if (hasnext) attention_reg(xpref, ripref, eipref, sh_wal[nbuf]);
      } else if (w == 5) {
        if (hasnext) *(float4*)&sh_xp[nbuf][lane * 4] = xppref;
      } else if (w == 6) {
        if (hasnext) {
          sh_ro[nbuf][lane] = ropref;
          sh_eo[nbuf][lane] = eopref;
        }
      }
      bar_lds();

      // ---- E: m-update + mems (w8-15); er = eo since mcur==1 ---------------
      if (w >= 8) {
        const int idx = tid - 512;
        const int d = idx & 63;
        const int c8 = idx >> 6;
        const int s = (d & 7) << 2;
        const int mbase = d << 6;
        const int c0a = c8 << 3;
        const int c0b = c0a + 4;
        float4 ma = *(float4*)&sh_mt[mbase + (c0a ^ s)];
        float4 mb = *(float4*)&sh_mt[mbase + (c0b ^ s)];
        {
          const int e0 = sh_eo[buf][c0a + 0];
          const int e1 = sh_eo[buf][c0a + 1];
          const int e2_ = sh_eo[buf][c0a + 2];
          const int e3 = sh_eo[buf][c0a + 3];
          const float h0 = sh_hnew[(sh_ro[buf][c0a + 0] << 6) + d];
          const float h1 = sh_hnew[(sh_ro[buf][c0a + 1] << 6) + d];
          const float h2 = sh_hnew[(sh_ro[buf][c0a + 2] << 6) + d];
          const float h3 = sh_hnew[(sh_ro[buf][c0a + 3] << 6) + d];
          ma.x = e0 ? h0 : ma.x;
          ma.y = e1 ? h1 : ma.y;
          ma.z = e2_ ? h2 : ma.z;
          ma.w = e3 ? h3 : ma.w;
        }
        {
          const int e0 = sh_eo[buf][c0b + 0];
          const int e1 = sh_eo[buf][c0b + 1];
          const int e2_ = sh_eo[buf][c0b + 2];
          const int e3 = sh_eo[buf][c0b + 3];
          const float h0 = sh_hnew[(sh_ro[buf][c0b + 0] << 6) + d];
          const float h1 = sh_hnew[(sh_ro[buf][c0b + 1] << 6) + d];
          const float h2 = sh_hnew[(sh_ro[buf][c0b + 2] << 6) + d];
          const float h3 = sh_hnew[(sh_ro[buf][c0b + 3] << 6) + d];
          mb.x = e0 ? h0 : mb.x;
          mb.y = e1 ? h1 : mb.y;
          mb.z = e2_ ? h2 : mb.z;
          mb.w = e3 ? h3 : mb.w;
        }
        *(float4*)&sh_mt[mbase + (c0a ^ s)] = ma;
        *(float4*)&sh_mt[mbase + (c0b ^ s)] = mb;
        const size_t mbg = (bt * C_) * RD_ + d;
        mems[mbg + (size_t)(c0a + 0) * RD_] = ma.x;
        mems[mbg + (size_t)(c0a + 1) * RD_] = ma.y;
        mems[mbg + (size_t)(c0a + 2) * RD_] = ma.z;
        mems[mbg + (size_t)(c0a + 3) * RD_] = ma.w;
        mems[mbg + (size_t)(c0b + 0) * RD_] = mb.x;
        mems[mbg + (size_t)(c0b + 1) * RD_] = mb.y;
        mems[mbg + (size_t)(c0b + 2) * RD_] = mb.z;
        mems[mbg + (size_t)(c0b + 3) * RD_] = mb.w;
      }
      bar_lds();
    } else {
      // ============ m == 0 : copy step (2 barriers, no state math) ===========
      // hout = hprev, mout = mprev; only aggs/outs/mems + prefetch+attention.
      // ---- P1: outs (w0-3) | aggs + issue (w4) | issue (w5,6) | mems (w8+) -
      if (w < 4) {
        outs[bt * OUT_ + j] = hreg;
      } else if (w == 4) {
        if (hasnext) {
          xpref = *(const float4*)&X[(bt + 1) * D_ + lane * 4];
          ripref = Ri[(bt + 1) * C_ + lane];
          eipref = Ei[(bt + 1) * C_ + lane];
        }
        float s0 = sh_wal[buf][0][lane];
        float s1 = sh_wal[buf][1][lane];
        float s2 = sh_wal[buf][2][lane];
        float s3 = sh_wal[buf][3][lane];
        s0 = wave_sum(s0);
        s1 = wave_sum(s1);
        s2 = wave_sum(s2);
        s3 = wave_sum(s3);
        if (lane == 0) {
          float4 v = {s0, s1, s2, s3};
          *(float4*)&aggs[bt * R_] = v;
        }
      } else if (w == 5) {
        if (hasnext) xppref = *(const float4*)&XP[(bt + 1) * OUT_ + lane * 4];
      } else if (w == 6) {
        if (hasnext) {
          ropref = Ro[(bt + 1) * C_ + lane];
          eopref = Eo[(bt + 1) * C_ + lane];
        }
      } else if (w >= 8) {
        const int idx = tid - 512;
        const int d = idx & 63;
        const int c8 = idx >> 6;
        const int s = (d & 7) << 2;
        const int mbase = d << 6;
        const int c0a = c8 << 3;
        const int c0b = c0a + 4;
        const float4 ma = *(const float4*)&sh_mt[mbase + (c0a ^ s)];
        const float4 mb = *(const float4*)&sh_mt[mbase + (c0b ^ s)];
        const size_t mbg = (bt * C_) * RD_ + d;
        mems[mbg + (size_t)(c0a + 0) * RD_] = ma.x;
        mems[mbg + (size_t)(c0a + 1) * RD_] = ma.y;
        mems[mbg + (size_t)(c0a + 2) * RD_] = ma.z;
        mems[mbg + (size_t)(c0a + 3) * RD_] = ma.w;
        mems[mbg + (size_t)(c0b + 0) * RD_] = mb.x;
        mems[mbg + (size_t)(c0b + 1) * RD_] = mb.y;
        mems[mbg + (size_t)(c0b + 2) * RD_] = mb.z;
        mems[mbg + (size_t)(c0b + 3) * RD_] = mb.w;
      }
      mnextI = hasnext ? sh_M[t + 1] : 0;
      bar_lds();

      // ---- P2: attention(t+1) (w4) | writeback (w5,6) ----------------------
      if (w == 4) {
        if (hasnext) attention_reg(xpref, ripref, eipref, sh_wal[nbuf]);
      } else if (w == 5) {
        if (hasnext) *(float4*)&sh_xp[nbuf][lane * 4] = xppref;
      } else if (w == 6) {
        if (hasnext) {
          sh_ro[nbuf][lane] = ropref;
          sh_eo[nbuf][lane] = eopref;
        }
      }
      bar_lds();
    }

    mcurI = mnextI;
  }
}

// ---------------------------------------------------------------------------
extern "C" void kernel_launch(void* const* d_in, const int* in_sizes, int n_in,
                              void* d_out, int out_size, void* d_ws, size_t ws_size,
                              hipStream_t stream) {
  const float* X = (const float*)d_in[0];
  const int* M = (const int*)d_in[1];
  const int* Ei = (const int*)d_in[2];
  const int* Eo = (const int*)d_in[3];
  const int* Ri = (const int*)d_in[4];
  const int* Ro = (const int*)d_in[5];
  const float* W = (const float*)d_in[6];
  const float* U = (const float*)d_in[7];
  const float* Bv = (const float*)d_in[8];
  const float* Watt = (const float*)d_in[9];

  float* outs = (float*)d_out;
  float* mems = outs + (size_t)B_ * T_ * OUT_;
  float* aggs = mems + (size_t)B_ * T_ * C_ * RD_;
  float* XP = (float*)d_ws;  // 16384*256 f32 = 16.8 MB

  xpre_kernel<<<dim3(B_ * T_ / 32), dim3(256), 0, stream>>>(X, W, XP);
  gru_kernel<<<dim3(B_), dim3(1024), 0, stream>>>(X, M, Ei, Eo, Ri, Ro, U, Bv,
                                                  Watt, XP, outs, mems, aggs);
}

// Round 6
// 2186.902 us; speedup vs baseline: 1.1736x; 1.0013x over previous
//
#include <hip/hip_runtime.h>

#define B_   32
#define T_   512
#define D_   256
#define C_   64
#define R_   4
#define RD_  64
#define OUT_ 256

// ---------------------------------------------------------------------------
// lgkm-only barrier: publishes LDS writes without draining vmcnt.
__device__ __forceinline__ void bar_lds() {
  asm volatile("s_waitcnt lgkmcnt(0)" ::: "memory");
  __builtin_amdgcn_s_barrier();
  asm volatile("" ::: "memory");
}

__device__ __forceinline__ float wave_sum(float v) {
  v += __shfl_xor(v, 1);
  v += __shfl_xor(v, 2);
  v += __shfl_xor(v, 4);
  v += __shfl_xor(v, 8);
  v += __shfl_xor(v, 16);
  v += __shfl_xor(v, 32);
  return v;
}

// ---------------------------------------------------------------------------
// Xpre = X @ W   (16384 x 256) @ (256 x 256), f32
__global__ __launch_bounds__(256) void xpre_kernel(const float* __restrict__ X,
                                                   const float* __restrict__ W,
                                                   float* __restrict__ XP) {
  __shared__ __align__(16) float xs[32][D_];
  const int j = threadIdx.x;
  const int row0 = blockIdx.x * 32;
  for (int k = 0; k < 32; ++k)
    xs[k][j] = X[(size_t)(row0 + k) * D_ + j];
  __syncthreads();
  float acc[32];
#pragma unroll
  for (int k = 0; k < 32; ++k) acc[k] = 0.f;
  for (int d4 = 0; d4 < D_ / 4; ++d4) {
    const float w0 = W[(d4 * 4 + 0) * OUT_ + j];
    const float w1 = W[(d4 * 4 + 1) * OUT_ + j];
    const float w2 = W[(d4 * 4 + 2) * OUT_ + j];
    const float w3 = W[(d4 * 4 + 3) * OUT_ + j];
#pragma unroll
    for (int k = 0; k < 32; ++k) {
      const float4 x4 = *(const float4*)&xs[k][d4 * 4];
      acc[k] = fmaf(x4.x, w0, fmaf(x4.y, w1, fmaf(x4.z, w2, fmaf(x4.w, w3, acc[k]))));
    }
  }
  for (int k = 0; k < 32; ++k)
    XP[(size_t)(row0 + k) * OUT_ + j] = acc[k];
}

// ---------------------------------------------------------------------------
// Recurrent kernel A: one block (16 waves) per batch element.
// Writes ONLY hbuf (hnew at m=1 steps) and aggs. outs/mems are reconstructed
// by memsB/outsC afterwards (pure gathers over the hnew history).
// m=0 steps (M block-uniform): 1 barrier. m=1 steps: 4 barriers.
// m state lives TRANSPOSED+swizzled in LDS: (d,c) at word d*64 + (c^((d&7)<<2)).
__global__ __launch_bounds__(1024, 4) void gruA(
    const float* __restrict__ X, const int* __restrict__ M,
    const int* __restrict__ Ei, const int* __restrict__ Eo,
    const int* __restrict__ Ri, const int* __restrict__ Ro,
    const float* __restrict__ U, const float* __restrict__ Bv,
    const float* __restrict__ Watt, const float* __restrict__ XP,
    float* __restrict__ hbuf, float* __restrict__ aggs) {
  __shared__ __align__(16) float sh_xp[2][OUT_];
  __shared__ int sh_ro[2][C_];
  __shared__ int sh_eo[2][C_];
  __shared__ __align__(16) float sh_watt[R_][D_];
  __shared__ __align__(16) float sh_mt[C_ * RD_];
  __shared__ __align__(16) float sh_wal[2][R_][C_];
  __shared__ __align__(16) float sh_prev[OUT_];
  __shared__ __align__(16) float sh_hnew[OUT_];
  __shared__ __align__(16) float sh_pB[4][OUT_];
  __shared__ int sh_M[T_];

  const int tid = threadIdx.x;
  const int lane = tid & 63;
  const int w = tid >> 6;
  const int j = tid & 255;
  const int kq = tid >> 8;
  const int b = blockIdx.x;
  const size_t bt0 = (size_t)b * T_;

  // U chunk: ureg[i] = U[kq*64+i][j]  (AGPR-resident)
  float ureg[64];
#pragma unroll
  for (int i = 0; i < 64; ++i)
    ureg[i] = U[(size_t)((kq << 6) + i) * OUT_ + j];

  float breg = (tid < OUT_) ? Bv[tid] : 0.f;

  // static LDS init
  ((float*)sh_watt)[tid] = Watt[tid];
  for (int idx = tid; idx < C_ * RD_; idx += 1024) sh_mt[idx] = 0.f;
  if (tid < T_) sh_M[tid] = M[bt0 + tid];
  if (tid < OUT_) sh_xp[0][tid] = XP[bt0 * OUT_ + tid];
  if (tid >= OUT_ && tid < OUT_ + C_) sh_ro[0][tid - OUT_] = Ro[bt0 * C_ + (tid - OUT_)];
  if (tid >= OUT_ + C_ && tid < OUT_ + 2 * C_)
    sh_eo[0][tid - OUT_ - C_] = Eo[bt0 * C_ + (tid - OUT_ - C_)];
  __syncthreads();

  // attention (wave 4, in-register inputs): alpha rows -> wal
  auto attention_reg = [&](const float4& x4, int ric, int eic, float (*wal)[C_]) {
    const float4 w0 = *(const float4*)&sh_watt[0][lane * 4];
    const float4 w1 = *(const float4*)&sh_watt[1][lane * 4];
    const float4 w2 = *(const float4*)&sh_watt[2][lane * 4];
    const float4 w3 = *(const float4*)&sh_watt[3][lane * 4];
    float y0 = fmaf(x4.x, w0.x, fmaf(x4.y, w0.y, fmaf(x4.z, w0.z, x4.w * w0.w)));
    float y1 = fmaf(x4.x, w1.x, fmaf(x4.y, w1.y, fmaf(x4.z, w1.z, x4.w * w1.w)));
    float y2 = fmaf(x4.x, w2.x, fmaf(x4.y, w2.y, fmaf(x4.z, w2.z, x4.w * w2.w)));
    float y3 = fmaf(x4.x, w3.x, fmaf(x4.y, w3.y, fmaf(x4.z, w3.z, x4.w * w3.w)));
    y0 = wave_sum(y0);
    y1 = wave_sum(y1);
    y2 = wave_sum(y2);
    y3 = wave_sum(y3);
    float yv = (ric & 1) ? y1 : y0;
    const float yw = (ric & 1) ? y3 : y2;
    yv = (ric & 2) ? yw : yv;
    const float am = __expf(yv) * (float)eic;  // EPS=1e-100 underflows in f32
    const float tot = wave_sum(am);
    const float alpha = am / tot;
    wal[0][lane] = (ric == 0) ? alpha : 0.f;
    wal[1][lane] = (ric == 1) ? alpha : 0.f;
    wal[2][lane] = (ric == 2) ? alpha : 0.f;
    wal[3][lane] = (ric == 3) ? alpha : 0.f;
  };

  // prefetch pipeline registers
  float4 xA = {0, 0, 0, 0}, xB = {0, 0, 0, 0}, xpA = {0, 0, 0, 0};
  int riA = 0, riB = 0, eiA = 0, eiB = 0, roA = 0, eoA = 0;

  // prologue: attention(0) + fill pipeline (A = t=1 data, B = t=2 data)
  if (w == 4) {
    const float4 x0 = *(const float4*)&X[bt0 * D_ + lane * 4];
    const int ri0 = Ri[bt0 * C_ + lane];
    const int ei0 = Ei[bt0 * C_ + lane];
    attention_reg(x0, ri0, ei0, sh_wal[0]);
    xA = *(const float4*)&X[(bt0 + 1) * D_ + lane * 4];
    riA = Ri[(bt0 + 1) * C_ + lane];
    eiA = Ei[(bt0 + 1) * C_ + lane];
    xB = *(const float4*)&X[(bt0 + 2) * D_ + lane * 4];
    riB = Ri[(bt0 + 2) * C_ + lane];
    eiB = Ei[(bt0 + 2) * C_ + lane];
  } else if (w == 5) {
    xpA = *(const float4*)&XP[(bt0 + 1) * OUT_ + lane * 4];
  } else if (w == 6) {
    roA = Ro[(bt0 + 1) * C_ + lane];
    eoA = Eo[(bt0 + 1) * C_ + lane];
  }
  bar_lds();

  for (int t = 0; t < T_; ++t) {
    const int buf = t & 1, nbuf = buf ^ 1;
    const size_t bt = bt0 + t;
    const int mcur = __builtin_amdgcn_readfirstlane(sh_M[t]);
    float prevreg = 0.f;

    // ---- P1: prev if m=1 (w0-3) | aggs+attention(t+1)+pipeline (w4) |
    // ----     xp writeback+reissue (w5) | ro/eo writeback+reissue (w6) ------
    if (w < 4) {
      if (mcur) {
        const int d = lane;
        const int s = (d & 7) << 2;
        const int mbase = d << 6;
        float a0 = 0.f, a1 = 0.f, a2 = 0.f, a3 = 0.f;
#pragma unroll
        for (int c4 = 0; c4 < 16; ++c4) {
          const int c0 = c4 << 2;
          const float4 mv = *(const float4*)&sh_mt[mbase + (c0 ^ s)];
          const float4 wv = *(const float4*)&sh_wal[buf][w][c0];  // broadcast
          a0 = fmaf(wv.x, mv.x, a0);
          a1 = fmaf(wv.y, mv.y, a1);
          a2 = fmaf(wv.z, mv.z, a2);
          a3 = fmaf(wv.w, mv.w, a3);
        }
        prevreg = (a0 + a1) + (a2 + a3);
        sh_prev[(w << 6) + d] = prevreg;
      }
    } else if (w == 4) {
      float s0 = sh_wal[buf][0][lane];
      float s1 = sh_wal[buf][1][lane];
      float s2 = sh_wal[buf][2][lane];
      float s3 = sh_wal[buf][3][lane];
      s0 = wave_sum(s0);
      s1 = wave_sum(s1);
      s2 = wave_sum(s2);
      s3 = wave_sum(s3);
      if (lane == 0) {
        float4 v = {s0, s1, s2, s3};
        *(float4*)&aggs[bt * R_] = v;
      }
      if (t + 1 < T_) {
        attention_reg(xA, riA, eiA, sh_wal[nbuf]);
        xA = xB;
        riA = riB;
        eiA = eiB;
        if (t + 3 < T_) {
          xB = *(const float4*)&X[(bt + 3) * D_ + lane * 4];
          riB = Ri[(bt + 3) * C_ + lane];
          eiB = Ei[(bt + 3) * C_ + lane];
        }
      }
    } else if (w == 5) {
      if (t + 1 < T_) {
        *(float4*)&sh_xp[nbuf][lane * 4] = xpA;
        if (t + 2 < T_) xpA = *(const float4*)&XP[(bt + 2) * OUT_ + lane * 4];
      }
    } else if (w == 6) {
      if (t + 1 < T_) {
        sh_ro[nbuf][lane] = roA;
        sh_eo[nbuf][lane] = eoA;
        if (t + 2 < T_) {
          roA = Ro[(bt + 2) * C_ + lane];
          eoA = Eo[(bt + 2) * C_ + lane];
        }
      }
    }
    bar_lds();
    if (!mcur) continue;  // m=0: state unchanged, nothing else to do

    // ---- P2: h2h partials = prev @ U (all 16 waves, U in AGPRs) ------------
    {
      float s0 = 0.f, s1 = 0.f;
#pragma unroll
      for (int i4 = 0; i4 < 16; ++i4) {
        const float4 pv = *(const float4*)&sh_prev[(kq << 6) + i4 * 4];
        if (i4 & 1) {
          s1 = fmaf(pv.x, ureg[i4 * 4 + 0], s1);
          s1 = fmaf(pv.y, ureg[i4 * 4 + 1], s1);
          s1 = fmaf(pv.z, ureg[i4 * 4 + 2], s1);
          s1 = fmaf(pv.w, ureg[i4 * 4 + 3], s1);
        } else {
          s0 = fmaf(pv.x, ureg[i4 * 4 + 0], s0);
          s0 = fmaf(pv.y, ureg[i4 * 4 + 1], s0);
          s0 = fmaf(pv.z, ureg[i4 * 4 + 2], s0);
          s0 = fmaf(pv.w, ureg[i4 * 4 + 3], s0);
        }
      }
      sh_pB[kq][j] = s0 + s1;
    }
    bar_lds();

    // ---- P3: gates -> sh_hnew + hbuf (w0-3) --------------------------------
    if (w < 4) {
      const float h2h = (sh_pB[0][j] + sh_pB[1][j]) + (sh_pB[2][j] + sh_pB[3][j]);
      const float xpv = sh_xp[buf][j];
      const float s1 = xpv + h2h + breg;
      const float rg = 1.f / (1.f + __expf(-s1));
      const float targ = xpv + rg * h2h + breg;
      const float e2 = __expf(2.f * targ);
      const float ht = 1.f - 2.f / (e2 + 1.f);  // tanh(targ)
      const float hn = (1.f - rg) * prevreg + rg * ht;
      sh_hnew[j] = hn;
      hbuf[bt * OUT_ + j] = hn;  // fire-and-forget history write
    }
    bar_lds();

    // ---- P4: m-update in LDS (w8-15); er = eo since mcur==1 ----------------
    if (w >= 8) {
      const int idx = tid - 512;
      const int d = idx & 63;
      const int c8 = idx >> 6;
      const int s = (d & 7) << 2;
      const int mbase = d << 6;
      const int c0a = c8 << 3;
      const int c0b = c0a + 4;
      float4 ma = *(float4*)&sh_mt[mbase + (c0a ^ s)];
      float4 mb = *(float4*)&sh_mt[mbase + (c0b ^ s)];
      {
        const int e0 = sh_eo[buf][c0a + 0];
        const int e1 = sh_eo[buf][c0a + 1];
        const int e2_ = sh_eo[buf][c0a + 2];
        const int e3 = sh_eo[buf][c0a + 3];
        const float h0 = sh_hnew[(sh_ro[buf][c0a + 0] << 6) + d];
        const float h1 = sh_hnew[(sh_ro[buf][c0a + 1] << 6) + d];
        const float h2 = sh_hnew[(sh_ro[buf][c0a + 2] << 6) + d];
        const float h3 = sh_hnew[(sh_ro[buf][c0a + 3] << 6) + d];
        ma.x = e0 ? h0 : ma.x;
        ma.y = e1 ? h1 : ma.y;
        ma.z = e2_ ? h2 : ma.z;
        ma.w = e3 ? h3 : ma.w;
      }
      {
        const int e0 = sh_eo[buf][c0b + 0];
        const int e1 = sh_eo[buf][c0b + 1];
        const int e2_ = sh_eo[buf][c0b + 2];
        const int e3 = sh_eo[buf][c0b + 3];
        const float h0 = sh_hnew[(sh_ro[buf][c0b + 0] << 6) + d];
        const float h1 = sh_hnew[(sh_ro[buf][c0b + 1] << 6) + d];
        const float h2 = sh_hnew[(sh_ro[buf][c0b + 2] << 6) + d];
        const float h3 = sh_hnew[(sh_ro[buf][c0b + 3] << 6) + d];
        mb.x = e0 ? h0 : mb.x;
        mb.y = e1 ? h1 : mb.y;
        mb.z = e2_ ? h2 : mb.z;
        mb.w = e3 ? h3 : mb.w;
      }
      *(float4*)&sh_mt[mbase + (c0a ^ s)] = ma;
      *(float4*)&sh_mt[mbase + (c0b ^ s)] = mb;
    }
    bar_lds();
  }
}

// ---------------------------------------------------------------------------
// Kernel B: reconstruct mems[b,t,c,:] = hnew(tau)[ro(tau,c)*64 + :] where
// tau = last step <= t with M=1 & Eo=1, else 0. One block per (b,c).
__global__ __launch_bounds__(512) void memsB(const int* __restrict__ M,
                                             const int* __restrict__ Eo,
                                             const int* __restrict__ Ro,
                                             const float* __restrict__ hbuf,
                                             float* __restrict__ mems) {
  __shared__ int lastA[T_];
  const int tid = threadIdx.x;
  const int b = blockIdx.x >> 6;
  const int c = blockIdx.x & 63;
  const size_t bt0 = (size_t)b * T_;
  {
    const int upd = M[bt0 + tid] & Eo[(bt0 + tid) * C_ + c];
    lastA[tid] = upd ? tid : -1;
  }
  __syncthreads();
  for (int off = 1; off < T_; off <<= 1) {
    const int u = (tid >= off) ? lastA[tid - off] : -1;
    const int v = lastA[tid];
    __syncthreads();
    lastA[tid] = (u > v) ? u : v;
    __syncthreads();
  }
  const int d = tid & 63;
  const int t8 = tid >> 6;  // 0..7
  for (int tt = 0; tt < 64; ++tt) {
    const int t = (tt << 3) + t8;
    const int tau = lastA[t];
    float v = 0.f;
    if (tau >= 0) {
      const int rc = Ro[(bt0 + tau) * C_ + c];
      v = hbuf[(bt0 + tau) * OUT_ + (rc << 6) + d];
    }
    mems[((bt0 + t) * C_ + c) * RD_ + d] = v;
  }
}

// ---------------------------------------------------------------------------
// Kernel C: outs[b,t,:] = hnew(tauM) (tauM = last M=1 step <= t), else 0.
// IN PLACE on the hbuf/outs region, descending t (reads tau <= t only touch
// rows not yet overwritten; __syncthreads separates reads from writes).
__global__ __launch_bounds__(512) void outsC(const int* __restrict__ M,
                                             float* __restrict__ outs) {
  __shared__ int lastM[T_];
  const int tid = threadIdx.x;
  const int b = blockIdx.x;
  const size_t bt0 = (size_t)b * T_;
  lastM[tid] = M[bt0 + tid] ? tid : -1;
  __syncthreads();
  for (int off = 1; off < T_; off <<= 1) {
    const int u = (tid >= off) ? lastM[tid - off] : -1;
    const int v = lastM[tid];
    __syncthreads();
    lastM[tid] = (u > v) ? u : v;
    __syncthreads();
  }
  const int j = tid & 255;
  const int th = tid >> 8;  // 0,1
  for (int k = 0; k < 256; ++k) {
    const int t = 511 - (k << 1) - th;
    const int tau = lastM[t];
    const float v = (tau >= 0) ? outs[(bt0 + tau) * OUT_ + j] : 0.f;
    __syncthreads();
    outs[(bt0 + t) * OUT_ + j] = v;
  }
}

// ---------------------------------------------------------------------------
extern "C" void kernel_launch(void* const* d_in, const int* in_sizes, int n_in,
                              void* d_out, int out_size, void* d_ws, size_t ws_size,
                              hipStream_t stream) {
  const float* X = (const float*)d_in[0];
  const int* M = (const int*)d_in[1];
  const int* Ei = (const int*)d_in[2];
  const int* Eo = (const int*)d_in[3];
  const int* Ri = (const int*)d_in[4];
  const int* Ro = (const int*)d_in[5];
  const float* W = (const float*)d_in[6];
  const float* U = (const float*)d_in[7];
  const float* Bv = (const float*)d_in[8];
  const float* Watt = (const float*)d_in[9];

  float* outs = (float*)d_out;
  float* mems = outs + (size_t)B_ * T_ * OUT_;
  float* aggs = mems + (size_t)B_ * T_ * C_ * RD_;
  float* XP = (float*)d_ws;   // 16.8 MB
  float* hbuf = outs;         // hnew history aliases the outs region

  xpre_kernel<<<dim3(B_ * T_ / 32), dim3(256), 0, stream>>>(X, W, XP);
  gruA<<<dim3(B_), dim3(1024), 0, stream>>>(X, M, Ei, Eo, Ri, Ro, U, Bv, Watt,
                                            XP, hbuf, aggs);
  memsB<<<dim3(B_ * C_), dim3(512), 0, stream>>>(M, Eo, Ro, hbuf, mems);
  outsC<<<dim3(B_), dim3(512), 0, stream>>>(M, outs);
}

// Round 7
// 1726.034 us; speedup vs baseline: 1.4870x; 1.2670x over previous
//
#include <hip/hip_runtime.h>

#define B_   32
#define T_   512
#define D_   256
#define C_   64
#define R_   4
#define RD_  64
#define OUT_ 256

// ---------------------------------------------------------------------------
// lgkm-only barrier: publishes LDS writes without draining vmcnt.
__device__ __forceinline__ void bar_lds() {
  asm volatile("s_waitcnt lgkmcnt(0)" ::: "memory");
  __builtin_amdgcn_s_barrier();
  asm volatile("" ::: "memory");
}

// ---- DPP-based wave reductions (VALU pipe, no LDS round-trips) -------------
template <int CTRL>
__device__ __forceinline__ float dpp_add(float v) {
  int s = __builtin_amdgcn_update_dpp(0, __float_as_int(v), CTRL, 0xF, 0xF, true);
  return v + __int_as_float(s);
}
// all 16 lanes of each row end with the row-of-16 sum
__device__ __forceinline__ float row16_sum(float v) {
  v = dpp_add<0xB1>(v);   // quad_perm [1,0,3,2]
  v = dpp_add<0x4E>(v);   // quad_perm [2,3,0,1]
  v = dpp_add<0x141>(v);  // row_half_mirror
  v = dpp_add<0x140>(v);  // row_mirror
  return v;
}
__device__ __forceinline__ float rlane(float v, int l) {
  return __int_as_float(__builtin_amdgcn_readlane(__float_as_int(v), l));
}
__device__ __forceinline__ float wave_sum_dpp(float v) {
  const float r = row16_sum(v);
  return (rlane(r, 0) + rlane(r, 16)) + (rlane(r, 32) + rlane(r, 48));
}

// ---------------------------------------------------------------------------
// Xpre = X @ W   (16384 x 256) @ (256 x 256), f32
__global__ __launch_bounds__(256) void xpre_kernel(const float* __restrict__ X,
                                                   const float* __restrict__ W,
                                                   float* __restrict__ XP) {
  __shared__ __align__(16) float xs[32][D_];
  const int j = threadIdx.x;
  const int row0 = blockIdx.x * 32;
  for (int k = 0; k < 32; ++k)
    xs[k][j] = X[(size_t)(row0 + k) * D_ + j];
  __syncthreads();
  float acc[32];
#pragma unroll
  for (int k = 0; k < 32; ++k) acc[k] = 0.f;
  for (int d4 = 0; d4 < D_ / 4; ++d4) {
    const float w0 = W[(d4 * 4 + 0) * OUT_ + j];
    const float w1 = W[(d4 * 4 + 1) * OUT_ + j];
    const float w2 = W[(d4 * 4 + 2) * OUT_ + j];
    const float w3 = W[(d4 * 4 + 3) * OUT_ + j];
#pragma unroll
    for (int k = 0; k < 32; ++k) {
      const float4 x4 = *(const float4*)&xs[k][d4 * 4];
      acc[k] = fmaf(x4.x, w0, fmaf(x4.y, w1, fmaf(x4.z, w2, fmaf(x4.w, w3, acc[k]))));
    }
  }
  for (int k = 0; k < 32; ++k)
    XP[(size_t)(row0 + k) * OUT_ + j] = acc[k];
}

// ---------------------------------------------------------------------------
// Recurrent kernel A: one block (16 waves) per batch element.
// Writes ONLY hbuf (hnew at m=1 steps) and aggs; memsB/outsC reconstruct.
// m=0 steps: 1 barrier. m=1 steps: 4 barriers.
// All wave reductions are DPP (VALU); attention reads no LDS (x, Watt in regs).
// m state TRANSPOSED+swizzled in LDS: (d,c) at word d*64 + (c^((d&7)<<2)).
__global__ __launch_bounds__(1024, 4) void gruA(
    const float* __restrict__ X, const int* __restrict__ M,
    const int* __restrict__ Ei, const int* __restrict__ Eo,
    const int* __restrict__ Ri, const int* __restrict__ Ro,
    const float* __restrict__ U, const float* __restrict__ Bv,
    const float* __restrict__ Watt, const float* __restrict__ XP,
    float* __restrict__ hbuf, float* __restrict__ aggs) {
  __shared__ __align__(16) float sh_xp[2][OUT_];
  __shared__ int sh_ro[2][C_];
  __shared__ int sh_eo[2][C_];
  __shared__ __align__(16) float sh_mt[C_ * RD_];
  __shared__ __align__(16) float sh_wal[2][R_][C_];
  __shared__ __align__(16) float sh_prev[OUT_];
  __shared__ __align__(16) float sh_hnew[OUT_];
  __shared__ __align__(16) float sh_pB[4][OUT_];
  __shared__ int sh_M[T_];

  const int tid = threadIdx.x;
  const int lane = tid & 63;
  const int w = tid >> 6;
  const int j = tid & 255;
  const int kq = tid >> 8;
  const int b = blockIdx.x;
  const size_t bt0 = (size_t)b * T_;

  // U chunk: ureg[i] = U[kq*64+i][j]  (AGPR-resident)
  float ureg[64];
#pragma unroll
  for (int i = 0; i < 64; ++i)
    ureg[i] = U[(size_t)((kq << 6) + i) * OUT_ + j];

  float breg = (tid < OUT_) ? Bv[tid] : 0.f;

  // static LDS init
  for (int idx = tid; idx < C_ * RD_; idx += 1024) sh_mt[idx] = 0.f;
  if (tid < T_) sh_M[tid] = M[bt0 + tid];
  if (tid < OUT_) sh_xp[0][tid] = XP[bt0 * OUT_ + tid];
  if (tid >= OUT_ && tid < OUT_ + C_) sh_ro[0][tid - OUT_] = Ro[bt0 * C_ + (tid - OUT_)];
  if (tid >= OUT_ + C_ && tid < OUT_ + 2 * C_)
    sh_eo[0][tid - OUT_ - C_] = Eo[bt0 * C_ + (tid - OUT_ - C_)];

  // wave-4 attention registers: Watt slice + x pipeline (remapped layout:
  // lane l covers elements d = (l&15)*16 .. +15 of attention row r = l>>4)
  const int r4 = lane >> 4, seg = lane & 15;
  float wq[16];
  float4 xA[4];
  int riA = 0, eiA = 0;
  float4 xpA = {0, 0, 0, 0};
  int roA = 0, eoA = 0;

  // attention for one step (wave 4 only): inputs in regs, out -> wal
  auto attention_dpp = [&](const float4* xr, int ric, int eic, float (*wal)[C_]) {
    float y = 0.f;
#pragma unroll
    for (int q = 0; q < 4; ++q) {
      y = fmaf(xr[q].x, wq[q * 4 + 0], y);
      y = fmaf(xr[q].y, wq[q * 4 + 1], y);
      y = fmaf(xr[q].z, wq[q * 4 + 2], y);
      y = fmaf(xr[q].w, wq[q * 4 + 3], y);
    }
    y = row16_sum(y);  // lanes of row r all hold y_r
    const float y0 = rlane(y, 0), y1 = rlane(y, 16);
    const float y2 = rlane(y, 32), y3 = rlane(y, 48);
    float yv = (ric & 1) ? y1 : y0;
    const float yw = (ric & 1) ? y3 : y2;
    yv = (ric & 2) ? yw : yv;
    const float am = __expf(yv) * (float)eic;  // EPS underflows in f32
    const float tot = wave_sum_dpp(am);
    const float alpha = __fdividef(am, tot);
    wal[0][lane] = (ric == 0) ? alpha : 0.f;
    wal[1][lane] = (ric == 1) ? alpha : 0.f;
    wal[2][lane] = (ric == 2) ? alpha : 0.f;
    wal[3][lane] = (ric == 3) ? alpha : 0.f;
  };

  __syncthreads();

  // prologue (wave 4): Watt regs, attention(0), pipeline fill for t=1
  if (w == 4) {
#pragma unroll
    for (int q = 0; q < 4; ++q) {
      const float4 t = *(const float4*)&Watt[(r4 << 8) + (seg << 4) + (q << 2)];
      wq[q * 4 + 0] = t.x; wq[q * 4 + 1] = t.y;
      wq[q * 4 + 2] = t.z; wq[q * 4 + 3] = t.w;
    }
    float4 x0[4];
#pragma unroll
    for (int q = 0; q < 4; ++q)
      x0[q] = *(const float4*)&X[bt0 * D_ + (seg << 4) + (q << 2)];
    const int ri0 = Ri[bt0 * C_ + lane];
    const int ei0 = Ei[bt0 * C_ + lane];
    attention_dpp(x0, ri0, ei0, sh_wal[0]);
#pragma unroll
    for (int q = 0; q < 4; ++q)
      xA[q] = *(const float4*)&X[(bt0 + 1) * D_ + (seg << 4) + (q << 2)];
    riA = Ri[(bt0 + 1) * C_ + lane];
    eiA = Ei[(bt0 + 1) * C_ + lane];
  } else if (w == 5) {
    xpA = *(const float4*)&XP[(bt0 + 1) * OUT_ + lane * 4];
  } else if (w == 6) {
    roA = Ro[(bt0 + 1) * C_ + lane];
    eoA = Eo[(bt0 + 1) * C_ + lane];
  }
  int mcur = M[bt0];
  bar_lds();

  for (int t = 0; t < T_; ++t) {
    const int buf = t & 1, nbuf = buf ^ 1;
    const size_t bt = bt0 + t;
    const bool hasnext = (t + 1 < T_);
    float prevreg = 0.f;

    // ---- P1: prev if m=1 (w0-3) | attention(t+1)+x reload (w4) |
    // ----     xp writeback+reissue (w5) | ro/eo writeback+reissue (w6) |
    // ----     aggs via DPP (w7) ---------------------------------------------
    if (w < 4) {
      if (mcur) {
        const int d = lane;
        const int s = (d & 7) << 2;
        const int mbase = d << 6;
        float a0 = 0.f, a1 = 0.f, a2 = 0.f, a3 = 0.f;
#pragma unroll
        for (int c4 = 0; c4 < 16; ++c4) {
          const int c0 = c4 << 2;
          const float4 mv = *(const float4*)&sh_mt[mbase + (c0 ^ s)];
          const float4 wv = *(const float4*)&sh_wal[buf][w][c0];  // broadcast
          a0 = fmaf(wv.x, mv.x, a0);
          a1 = fmaf(wv.y, mv.y, a1);
          a2 = fmaf(wv.z, mv.z, a2);
          a3 = fmaf(wv.w, mv.w, a3);
        }
        prevreg = (a0 + a1) + (a2 + a3);
        sh_prev[(w << 6) + d] = prevreg;
      }
    } else if (w == 4) {
      if (hasnext) {
        attention_dpp(xA, riA, eiA, sh_wal[nbuf]);
        if (t + 2 < T_) {
#pragma unroll
          for (int q = 0; q < 4; ++q)
            xA[q] = *(const float4*)&X[(bt + 2) * D_ + (seg << 4) + (q << 2)];
          riA = Ri[(bt + 2) * C_ + lane];
          eiA = Ei[(bt + 2) * C_ + lane];
        }
      }
    } else if (w == 5) {
      if (hasnext) {
        *(float4*)&sh_xp[nbuf][lane * 4] = xpA;
        if (t + 2 < T_) xpA = *(const float4*)&XP[(bt + 2) * OUT_ + lane * 4];
      }
    } else if (w == 6) {
      if (hasnext) {
        sh_ro[nbuf][lane] = roA;
        sh_eo[nbuf][lane] = eoA;
        if (t + 2 < T_) {
          roA = Ro[(bt + 2) * C_ + lane];
          eoA = Eo[(bt + 2) * C_ + lane];
        }
      }
    } else if (w == 7) {
      const float v0 = sh_wal[buf][0][lane];
      const float v1 = sh_wal[buf][1][lane];
      const float v2 = sh_wal[buf][2][lane];
      const float v3 = sh_wal[buf][3][lane];
      const float s0 = wave_sum_dpp(v0);
      const float s1 = wave_sum_dpp(v1);
      const float s2 = wave_sum_dpp(v2);
      const float s3 = wave_sum_dpp(v3);
      if (lane == 0) {
        float4 v = {s0, s1, s2, s3};
        *(float4*)&aggs[bt * R_] = v;
      }
    }
    const int mnxt = hasnext ? sh_M[t + 1] : 0;
    bar_lds();

    if (!mcur) {
      mcur = mnxt;
      continue;
    }

    // ---- P2: h2h partials = prev @ U (all 16 waves, U in AGPRs) ------------
    {
      float s0 = 0.f, s1 = 0.f;
#pragma unroll
      for (int i4 = 0; i4 < 16; ++i4) {
        const float4 pv = *(const float4*)&sh_prev[(kq << 6) + i4 * 4];
        if (i4 & 1) {
          s1 = fmaf(pv.x, ureg[i4 * 4 + 0], s1);
          s1 = fmaf(pv.y, ureg[i4 * 4 + 1], s1);
          s1 = fmaf(pv.z, ureg[i4 * 4 + 2], s1);
          s1 = fmaf(pv.w, ureg[i4 * 4 + 3], s1);
        } else {
          s0 = fmaf(pv.x, ureg[i4 * 4 + 0], s0);
          s0 = fmaf(pv.y, ureg[i4 * 4 + 1], s0);
          s0 = fmaf(pv.z, ureg[i4 * 4 + 2], s0);
          s0 = fmaf(pv.w, ureg[i4 * 4 + 3], s0);
        }
      }
      sh_pB[kq][j] = s0 + s1;
    }
    bar_lds();

    // ---- P3: gates -> sh_hnew + hbuf (w0-3) --------------------------------
    if (w < 4) {
      const float h2h = (sh_pB[0][j] + sh_pB[1][j]) + (sh_pB[2][j] + sh_pB[3][j]);
      const float xpv = sh_xp[buf][j];
      const float s1 = xpv + h2h + breg;
      const float rg = 1.f / (1.f + __expf(-s1));
      const float targ = xpv + rg * h2h + breg;
      const float e2 = __expf(2.f * targ);
      const float ht = 1.f - 2.f / (e2 + 1.f);  // tanh(targ)
      const float hn = (1.f - rg) * prevreg + rg * ht;
      sh_hnew[j] = hn;
      hbuf[bt * OUT_ + j] = hn;  // fire-and-forget history write
    }
    bar_lds();

    // ---- P4: m-update in LDS (w8-15); er = eo since mcur==1 ----------------
    if (w >= 8) {
      const int idx = tid - 512;
      const int d = idx & 63;
      const int c8 = idx >> 6;
      const int s = (d & 7) << 2;
      const int mbase = d << 6;
      const int c0a = c8 << 3;
      const int c0b = c0a + 4;
      float4 ma = *(float4*)&sh_mt[mbase + (c0a ^ s)];
      float4 mb = *(float4*)&sh_mt[mbase + (c0b ^ s)];
      {
        const int e0 = sh_eo[buf][c0a + 0];
        const int e1 = sh_eo[buf][c0a + 1];
        const int e2_ = sh_eo[buf][c0a + 2];
        const int e3 = sh_eo[buf][c0a + 3];
        const float h0 = sh_hnew[(sh_ro[buf][c0a + 0] << 6) + d];
        const float h1 = sh_hnew[(sh_ro[buf][c0a + 1] << 6) + d];
        const float h2 = sh_hnew[(sh_ro[buf][c0a + 2] << 6) + d];
        const float h3 = sh_hnew[(sh_ro[buf][c0a + 3] << 6) + d];
        ma.x = e0 ? h0 : ma.x;
        ma.y = e1 ? h1 : ma.y;
        ma.z = e2_ ? h2 : ma.z;
        ma.w = e3 ? h3 : ma.w;
      }
      {
        const int e0 = sh_eo[buf][c0b + 0];
        const int e1 = sh_eo[buf][c0b + 1];
        const int e2_ = sh_eo[buf][c0b + 2];
        const int e3 = sh_eo[buf][c0b + 3];
        const float h0 = sh_hnew[(sh_ro[buf][c0b + 0] << 6) + d];
        const float h1 = sh_hnew[(sh_ro[buf][c0b + 1] << 6) + d];
        const float h2 = sh_hnew[(sh_ro[buf][c0b + 2] << 6) + d];
        const float h3 = sh_hnew[(sh_ro[buf][c0b + 3] << 6) + d];
        mb.x = e0 ? h0 : mb.x;
        mb.y = e1 ? h1 : mb.y;
        mb.z = e2_ ? h2 : mb.z;
        mb.w = e3 ? h3 : mb.w;
      }
      *(float4*)&sh_mt[mbase + (c0a ^ s)] = ma;
      *(float4*)&sh_mt[mbase + (c0b ^ s)] = mb;
    }
    bar_lds();

    mcur = mnxt;
  }
}

// ---------------------------------------------------------------------------
// Kernel B: mems[b,t,c,:] = hnew(tau)[ro(tau,c)*64 + :], tau = last step <= t
// with M=1 & Eo=1, else 0. One block per (b,c).
__global__ __launch_bounds__(512) void memsB(const int* __restrict__ M,
                                             const int* __restrict__ Eo,
                                             const int* __restrict__ Ro,
                                             const float* __restrict__ hbuf,
                                             float* __restrict__ mems) {
  __shared__ int lastA[T_];
  const int tid = threadIdx.x;
  const int b = blockIdx.x >> 6;
  const int c = blockIdx.x & 63;
  const size_t bt0 = (size_t)b * T_;
  {
    const int upd = M[bt0 + tid] & Eo[(bt0 + tid) * C_ + c];
    lastA[tid] = upd ? tid : -1;
  }
  __syncthreads();
  for (int off = 1; off < T_; off <<= 1) {
    const int u = (tid >= off) ? lastA[tid - off] : -1;
    const int v = lastA[tid];
    __syncthreads();
    lastA[tid] = (u > v) ? u : v;
    __syncthreads();
  }
  const int d = tid & 63;
  const int t8 = tid >> 6;
  for (int tt = 0; tt < 64; ++tt) {
    const int t = (tt << 3) + t8;
    const int tau = lastA[t];
    float v = 0.f;
    if (tau >= 0) {
      const int rc = Ro[(bt0 + tau) * C_ + c];
      v = hbuf[(bt0 + tau) * OUT_ + (rc << 6) + d];
    }
    mems[((bt0 + t) * C_ + c) * RD_ + d] = v;
  }
}

// ---------------------------------------------------------------------------
// Kernel C: outs[b,t,:] = hnew(tauM), tauM = last M=1 step <= t, else 0.
// In place on hbuf/outs, descending t.
__global__ __launch_bounds__(512) void outsC(const int* __restrict__ M,
                                             float* __restrict__ outs) {
  __shared__ int lastM[T_];
  const int tid = threadIdx.x;
  const int b = blockIdx.x;
  const size_t bt0 = (size_t)b * T_;
  lastM[tid] = M[bt0 + tid] ? tid : -1;
  __syncthreads();
  for (int off = 1; off < T_; off <<= 1) {
    const int u = (tid >= off) ? lastM[tid - off] : -1;
    const int v = lastM[tid];
    __syncthreads();
    lastM[tid] = (u > v) ? u : v;
    __syncthreads();
  }
  const int j = tid & 255;
  const int th = tid >> 8;
  for (int k = 0; k < 256; ++k) {
    const int t = 511 - (k << 1) - th;
    const int tau = lastM[t];
    const float v = (tau >= 0) ? outs[(bt0 + tau) * OUT_ + j] : 0.f;
    __syncthreads();
    outs[(bt0 + t) * OUT_ + j] = v;
  }
}

// ---------------------------------------------------------------------------
extern "C" void kernel_launch(void* const* d_in, const int* in_sizes, int n_in,
                              void* d_out, int out_size, void* d_ws, size_t ws_size,
                              hipStream_t stream) {
  const float* X = (const float*)d_in[0];
  const int* M = (const int*)d_in[1];
  const int* Ei = (const int*)d_in[2];
  const int* Eo = (const int*)d_in[3];
  const int* Ri = (const int*)d_in[4];
  const int* Ro = (const int*)d_in[5];
  const float* W = (const float*)d_in[6];
  const float* U = (const float*)d_in[7];
  const float* Bv = (const float*)d_in[8];
  const float* Watt = (const float*)d_in[9];

  float* outs = (float*)d_out;
  float* mems = outs + (size_t)B_ * T_ * OUT_;
  float* aggs = mems + (size_t)B_ * T_ * C_ * RD_;
  float* XP = (float*)d_ws;   // 16.8 MB
  float* hbuf = outs;         // hnew history aliases the outs region

  xpre_kernel<<<dim3(B_ * T_ / 32), dim3(256), 0, stream>>>(X, W, XP);
  gruA<<<dim3(B_), dim3(1024), 0, stream>>>(X, M, Ei, Eo, Ri, Ro, U, Bv, Watt,
                                            XP, hbuf, aggs);
  memsB<<<dim3(B_ * C_), dim3(512), 0, stream>>>(M, Eo, Ro, hbuf, mems);
  outsC<<<dim3(B_), dim3(512), 0, stream>>>(M, outs);
}

// Round 8
// 1283.513 us; speedup vs baseline: 1.9997x; 1.3448x over previous
//
#include <hip/hip_runtime.h>

#define B_   32
#define T_   512
#define D_   256
#define C_   64
#define R_   4
#define RD_  64
#define OUT_ 256

// ---------------------------------------------------------------------------
__device__ __forceinline__ void bar_lds() {
  asm volatile("s_waitcnt lgkmcnt(0)" ::: "memory");
  __builtin_amdgcn_s_barrier();
  asm volatile("" ::: "memory");
}

// ---- DPP-based wave reductions (VALU pipe) ---------------------------------
template <int CTRL>
__device__ __forceinline__ float dpp_add(float v) {
  int s = __builtin_amdgcn_update_dpp(0, __float_as_int(v), CTRL, 0xF, 0xF, true);
  return v + __int_as_float(s);
}
__device__ __forceinline__ float row16_sum(float v) {
  v = dpp_add<0xB1>(v);   // quad_perm [1,0,3,2]
  v = dpp_add<0x4E>(v);   // quad_perm [2,3,0,1]
  v = dpp_add<0x141>(v);  // row_half_mirror
  v = dpp_add<0x140>(v);  // row_mirror
  return v;
}
__device__ __forceinline__ float rlane(float v, int l) {
  return __int_as_float(__builtin_amdgcn_readlane(__float_as_int(v), l));
}
__device__ __forceinline__ float wave_sum_dpp(float v) {
  const float r = row16_sum(v);
  return (rlane(r, 0) + rlane(r, 16)) + (rlane(r, 32) + rlane(r, 48));
}

// ---------------------------------------------------------------------------
// Xpre = X @ W   (16384 x 256) @ (256 x 256), f32
__global__ __launch_bounds__(256) void xpre_kernel(const float* __restrict__ X,
                                                   const float* __restrict__ W,
                                                   float* __restrict__ XP) {
  __shared__ __align__(16) float xs[32][D_];
  const int j = threadIdx.x;
  const int row0 = blockIdx.x * 32;
  for (int k = 0; k < 32; ++k)
    xs[k][j] = X[(size_t)(row0 + k) * D_ + j];
  __syncthreads();
  float acc[32];
#pragma unroll
  for (int k = 0; k < 32; ++k) acc[k] = 0.f;
  for (int d4 = 0; d4 < D_ / 4; ++d4) {
    const float w0 = W[(d4 * 4 + 0) * OUT_ + j];
    const float w1 = W[(d4 * 4 + 1) * OUT_ + j];
    const float w2 = W[(d4 * 4 + 2) * OUT_ + j];
    const float w3 = W[(d4 * 4 + 3) * OUT_ + j];
#pragma unroll
    for (int k = 0; k < 32; ++k) {
      const float4 x4 = *(const float4*)&xs[k][d4 * 4];
      acc[k] = fmaf(x4.x, w0, fmaf(x4.y, w1, fmaf(x4.z, w2, fmaf(x4.w, w3, acc[k]))));
    }
  }
  for (int k = 0; k < 32; ++k)
    XP[(size_t)(row0 + k) * OUT_ + j] = acc[k];
}

// ---------------------------------------------------------------------------
// attnK: attention weights + aggs for ALL (b,t) — independent of recurrence.
// One wave per (b,t). walG[bt*256 + r*64 + c] = (ri[c]==r ? alpha[c] : 0).
__global__ __launch_bounds__(256) void attnK(const float* __restrict__ X,
                                             const int* __restrict__ Ri,
                                             const int* __restrict__ Ei,
                                             const float* __restrict__ Watt,
                                             float* __restrict__ walG,
                                             float* __restrict__ aggs) {
  const int wv = threadIdx.x >> 6;
  const int lane = threadIdx.x & 63;
  const size_t bt = (size_t)blockIdx.x * 4 + wv;
  const int r4 = lane >> 4, seg = lane & 15;

  float y = 0.f;
#pragma unroll
  for (int q = 0; q < 4; ++q) {
    const float4 wt = *(const float4*)&Watt[(r4 << 8) + (seg << 4) + (q << 2)];
    const float4 xv = *(const float4*)&X[bt * D_ + (seg << 4) + (q << 2)];
    y = fmaf(xv.x, wt.x, y);
    y = fmaf(xv.y, wt.y, y);
    y = fmaf(xv.z, wt.z, y);
    y = fmaf(xv.w, wt.w, y);
  }
  y = row16_sum(y);
  const float y0 = rlane(y, 0), y1 = rlane(y, 16);
  const float y2 = rlane(y, 32), y3 = rlane(y, 48);
  const int ric = Ri[bt * C_ + lane];
  const float eic = (float)Ei[bt * C_ + lane];
  float yv = (ric & 1) ? y1 : y0;
  const float yw = (ric & 1) ? y3 : y2;
  yv = (ric & 2) ? yw : yv;
  const float am = __expf(yv) * eic;  // EPS=1e-100 underflows in f32
  const float tot = wave_sum_dpp(am);
  const float alpha = __fdividef(am, tot);

  const float w0 = (ric == 0) ? alpha : 0.f;
  const float w1 = (ric == 1) ? alpha : 0.f;
  const float w2 = (ric == 2) ? alpha : 0.f;
  const float w3 = (ric == 3) ? alpha : 0.f;
  walG[bt * 256 + 0 * C_ + lane] = w0;
  walG[bt * 256 + 1 * C_ + lane] = w1;
  walG[bt * 256 + 2 * C_ + lane] = w2;
  walG[bt * 256 + 3 * C_ + lane] = w3;
  const float s0 = wave_sum_dpp(w0);
  const float s1 = wave_sum_dpp(w1);
  const float s2 = wave_sum_dpp(w2);
  const float s3 = wave_sum_dpp(w3);
  if (lane == 0) {
    float4 v = {s0, s1, s2, s3};
    *(float4*)&aggs[bt * R_] = v;
  }
}

// ---------------------------------------------------------------------------
// gruA: recurrent core. 256 threads (4 waves, 1/SIMD, 512-reg budget).
// Iterates ONLY over m=1 steps (tlist). Per iteration: 3 barriers.
// Thread tid owns output j=tid: prev[j] (P1), h2h[j]+gates (P2, U fully
// in registers ureg[256]), m-update (P3, 16 elems/thread).
// m state TRANSPOSED+swizzled: (d,c) at word d*64 + (c^((d&7)<<2)).
__global__ __launch_bounds__(256, 1) void gruA(
    const int* __restrict__ M, const int* __restrict__ Eo,
    const int* __restrict__ Ro, const float* __restrict__ U,
    const float* __restrict__ Bv, const float* __restrict__ XP,
    const float* __restrict__ walG, float* __restrict__ hbuf) {
  __shared__ __align__(16) float sh_wal[2][256];
  __shared__ __align__(16) float sh_xp[2][256];
  __shared__ int sh_ro[2][C_];
  __shared__ int sh_eo[2][C_];
  __shared__ __align__(16) float sh_mt[C_ * RD_];
  __shared__ __align__(16) float sh_prev[OUT_];
  __shared__ __align__(16) float sh_hnew[OUT_];
  __shared__ int sh_tl[T_];
  __shared__ int sh_nT;

  const int tid = threadIdx.x;
  const int lane = tid & 63;
  const int w = tid >> 6;
  const int b = blockIdx.x;
  const size_t bt0 = (size_t)b * T_;

  // U column j=tid fully in registers (AGPR-backed at 1 wave/SIMD budget)
  float ureg[256];
#pragma unroll
  for (int i = 0; i < 256; ++i)
    ureg[i] = U[(size_t)i * OUT_ + tid];
  const float breg = Bv[tid];

  // zero m state
#pragma unroll
  for (int i = 0; i < 16; ++i) sh_mt[tid + (i << 8)] = 0.f;

  // tlist: indices of m=1 steps (wave 0, ballot prefix scan)
  if (tid < 64) {
    int base = 0;
    for (int ch = 0; ch < 8; ++ch) {
      const int mv = M[bt0 + (ch << 6) + lane];
      const unsigned long long mask = __ballot(mv != 0);
      if (mv) {
        const unsigned long long lt = ((lane == 63) ? ~0ull : ((1ull << (lane + 1)) - 1)) >> 1;
        sh_tl[base + __popcll(mask & lt)] = (ch << 6) + lane;
      }
      base += __popcll(mask);
    }
    if (lane == 0) sh_nT = base;
  }
  __syncthreads();
  const int nT = sh_nT;
  if (nT == 0) return;

  // prologue: buffer 0 <- t0; parity-set S1 <- t1
  {
    const int t0 = sh_tl[0];
    sh_wal[0][tid] = walG[(bt0 + t0) * 256 + tid];
    sh_xp[0][tid] = XP[(bt0 + t0) * 256 + tid];
    if (tid < 64) {
      sh_ro[0][tid] = Ro[(bt0 + t0) * C_ + tid];
      sh_eo[0][tid] = Eo[(bt0 + t0) * C_ + tid];
    }
  }
  float walS0 = 0.f, xpS0 = 0.f, walS1 = 0.f, xpS1 = 0.f;
  int roS0 = 0, eoS0 = 0, roS1 = 0, eoS1 = 0;
  if (nT > 1) {
    const int t1 = sh_tl[1];
    walS1 = walG[(bt0 + t1) * 256 + tid];
    xpS1 = XP[(bt0 + t1) * 256 + tid];
    if (tid < 64) {
      roS1 = Ro[(bt0 + t1) * C_ + tid];
      eoS1 = Eo[(bt0 + t1) * C_ + tid];
    }
  }
  __syncthreads();

  const int d = lane;
  const int s = (d & 7) << 2;
  const int mbase = d << 6;

  // One m=1 step. I-set: registers to ISSUE loads for t_{k+2}.
  // W-set: registers holding t_{k+1} data, WRITTEN to LDS in P2.
  auto do_step = [&](int k, float& walI, float& xpI, int& roI, int& eoI,
                     float& walW, float& xpW, int& roW, int& eoW) {
    const int cur = k & 1, nxt = cur ^ 1;
    const int tk = sh_tl[k];
    const size_t bt = bt0 + tk;
    const bool hn1 = (k + 1 < nT);

    // ---- P1: issue prefetch (k+2) + prev GEMV ----
    if (k + 2 < nT) {
      const int t2 = sh_tl[k + 2];
      walI = walG[(bt0 + t2) * 256 + tid];
      xpI = XP[(bt0 + t2) * 256 + tid];
      if (tid < 64) {
        roI = Ro[(bt0 + t2) * C_ + tid];
        eoI = Eo[(bt0 + t2) * C_ + tid];
      }
    }
    float a0 = 0.f, a1 = 0.f, a2 = 0.f, a3 = 0.f;
#pragma unroll
    for (int c4 = 0; c4 < 16; ++c4) {
      const int c0 = c4 << 2;
      const float4 mv = *(const float4*)&sh_mt[mbase + (c0 ^ s)];
      const float4 wv = *(const float4*)&sh_wal[cur][(w << 6) + c0];  // bcast
      a0 = fmaf(wv.x, mv.x, a0);
      a1 = fmaf(wv.y, mv.y, a1);
      a2 = fmaf(wv.z, mv.z, a2);
      a3 = fmaf(wv.w, mv.w, a3);
    }
    const float prevreg = (a0 + a1) + (a2 + a3);
    sh_prev[tid] = prevreg;
    bar_lds();

    // ---- P2: h2h (U in regs) + gates + prefetch writeback ----
    float s0 = 0.f, s1 = 0.f, s2 = 0.f, s3 = 0.f;
#pragma unroll
    for (int i = 0; i < 64; ++i) {
      const float4 pv = *(const float4*)&sh_prev[i << 2];  // bcast
      s0 = fmaf(pv.x, ureg[(i << 2) + 0], s0);
      s1 = fmaf(pv.y, ureg[(i << 2) + 1], s1);
      s2 = fmaf(pv.z, ureg[(i << 2) + 2], s2);
      s3 = fmaf(pv.w, ureg[(i << 2) + 3], s3);
    }
    const float h2h = (s0 + s1) + (s2 + s3);
    const float xpv = sh_xp[cur][tid];
    const float g1 = xpv + h2h + breg;
    const float rg = 1.f / (1.f + __expf(-g1));
    const float targ = xpv + rg * h2h + breg;
    const float e2 = __expf(2.f * targ);
    const float ht = 1.f - 2.f / (e2 + 1.f);  // tanh
    const float hn = (1.f - rg) * prevreg + rg * ht;
    sh_hnew[tid] = hn;
    hbuf[bt * OUT_ + tid] = hn;
    if (hn1) {
      sh_wal[nxt][tid] = walW;
      sh_xp[nxt][tid] = xpW;
      if (tid < 64) {
        sh_ro[nxt][tid] = roW;
        sh_eo[nxt][tid] = eoW;
      }
    }
    bar_lds();

    // ---- P3: m-update (16 elems/thread: c = w*16..+15 at row d) ----
#pragma unroll
    for (int q = 0; q < 4; ++q) {
      const int c0 = (w << 4) + (q << 2);
      float4 mm = *(float4*)&sh_mt[mbase + (c0 ^ s)];
      const float h0 = sh_hnew[(sh_ro[cur][c0 + 0] << 6) + d];
      const float h1 = sh_hnew[(sh_ro[cur][c0 + 1] << 6) + d];
      const float h2 = sh_hnew[(sh_ro[cur][c0 + 2] << 6) + d];
      const float h3 = sh_hnew[(sh_ro[cur][c0 + 3] << 6) + d];
      mm.x = sh_eo[cur][c0 + 0] ? h0 : mm.x;
      mm.y = sh_eo[cur][c0 + 1] ? h1 : mm.y;
      mm.z = sh_eo[cur][c0 + 2] ? h2 : mm.z;
      mm.w = sh_eo[cur][c0 + 3] ? h3 : mm.w;
      *(float4*)&sh_mt[mbase + (c0 ^ s)] = mm;
    }
    bar_lds();
  };

  for (int k = 0; k < nT; k += 2) {
    do_step(k, walS0, xpS0, roS0, eoS0, walS1, xpS1, roS1, eoS1);
    if (k + 1 < nT)
      do_step(k + 1, walS1, xpS1, roS1, eoS1, walS0, xpS0, roS0, eoS0);
  }
}

// ---------------------------------------------------------------------------
// memsB: mems[b,t,c,:] = hbuf(tau)[ro(tau,c)*64+:], tau = last step<=t with
// M&Eo, else 0. One block per (b,c).
__global__ __launch_bounds__(512) void memsB(const int* __restrict__ M,
                                             const int* __restrict__ Eo,
                                             const int* __restrict__ Ro,
                                             const float* __restrict__ hbuf,
                                             float* __restrict__ mems) {
  __shared__ int lastA[T_];
  const int tid = threadIdx.x;
  const int b = blockIdx.x >> 6;
  const int c = blockIdx.x & 63;
  const size_t bt0 = (size_t)b * T_;
  {
    const int upd = M[bt0 + tid] & Eo[(bt0 + tid) * C_ + c];
    lastA[tid] = upd ? tid : -1;
  }
  __syncthreads();
  for (int off = 1; off < T_; off <<= 1) {
    const int u = (tid >= off) ? lastA[tid - off] : -1;
    const int v = lastA[tid];
    __syncthreads();
    lastA[tid] = (u > v) ? u : v;
    __syncthreads();
  }
  const int d = tid & 63;
  const int t8 = tid >> 6;
  for (int tt = 0; tt < 64; ++tt) {
    const int t = (tt << 3) + t8;
    const int tau = lastA[t];
    float v = 0.f;
    if (tau >= 0) {
      const int rc = Ro[(bt0 + tau) * C_ + c];
      v = hbuf[(bt0 + tau) * OUT_ + (rc << 6) + d];
    }
    mems[((bt0 + t) * C_ + c) * RD_ + d] = v;
  }
}

// ---------------------------------------------------------------------------
// outsC: outs[b,t,:] = hbuf(tauM), tauM = last M=1 step <= t, else 0.
// In place on hbuf/outs, descending t.
__global__ __launch_bounds__(512) void outsC(const int* __restrict__ M,
                                             float* __restrict__ outs) {
  __shared__ int lastM[T_];
  const int tid = threadIdx.x;
  const int b = blockIdx.x;
  const size_t bt0 = (size_t)b * T_;
  lastM[tid] = M[bt0 + tid] ? tid : -1;
  __syncthreads();
  for (int off = 1; off < T_; off <<= 1) {
    const int u = (tid >= off) ? lastM[tid - off] : -1;
    const int v = lastM[tid];
    __syncthreads();
    lastM[tid] = (u > v) ? u : v;
    __syncthreads();
  }
  const int j = tid & 255;
  const int th = tid >> 8;
  for (int k = 0; k < 256; ++k) {
    const int t = 511 - (k << 1) - th;
    const int tau = lastM[t];
    const float v = (tau >= 0) ? outs[(bt0 + tau) * OUT_ + j] : 0.f;
    __syncthreads();
    outs[(bt0 + t) * OUT_ + j] = v;
  }
}

// ---------------------------------------------------------------------------
extern "C" void kernel_launch(void* const* d_in, const int* in_sizes, int n_in,
                              void* d_out, int out_size, void* d_ws, size_t ws_size,
                              hipStream_t stream) {
  const float* X = (const float*)d_in[0];
  const int* M = (const int*)d_in[1];
  const int* Ei = (const int*)d_in[2];
  const int* Eo = (const int*)d_in[3];
  const int* Ri = (const int*)d_in[4];
  const int* Ro = (const int*)d_in[5];
  const float* W = (const float*)d_in[6];
  const float* U = (const float*)d_in[7];
  const float* Bv = (const float*)d_in[8];
  const float* Watt = (const float*)d_in[9];

  float* outs = (float*)d_out;
  float* mems = outs + (size_t)B_ * T_ * OUT_;
  float* aggs = mems + (size_t)B_ * T_ * C_ * RD_;
  float* XP = (float*)d_ws;   // 16.8 MB scratch
  float* hbuf = outs;         // hnew history aliases outs (outsC finalizes)
  float* walG = mems;         // alpha scratch aliases mems (memsB overwrites)

  xpre_kernel<<<dim3(B_ * T_ / 32), dim3(256), 0, stream>>>(X, W, XP);
  attnK<<<dim3(B_ * T_ / 4), dim3(256), 0, stream>>>(X, Ri, Ei, Watt, walG, aggs);
  gruA<<<dim3(B_), dim3(256), 0, stream>>>(M, Eo, Ro, U, Bv, XP, walG, hbuf);
  memsB<<<dim3(B_ * C_), dim3(512), 0, stream>>>(M, Eo, Ro, hbuf, mems);
  outsC<<<dim3(B_), dim3(512), 0, stream>>>(M, outs);
}

// Round 9
// 1195.401 us; speedup vs baseline: 2.1471x; 1.0737x over previous
//
#include <hip/hip_runtime.h>

#define B_   32
#define T_   512
#define D_   256
#define C_   64
#define R_   4
#define RD_  64
#define OUT_ 256

// ---------------------------------------------------------------------------
__device__ __forceinline__ void bar_lds() {
  asm volatile("s_waitcnt lgkmcnt(0)" ::: "memory");
  __builtin_amdgcn_s_barrier();
  asm volatile("" ::: "memory");
}

// ---- DPP-based wave reductions (VALU pipe) ---------------------------------
template <int CTRL>
__device__ __forceinline__ float dpp_add(float v) {
  int s = __builtin_amdgcn_update_dpp(0, __float_as_int(v), CTRL, 0xF, 0xF, true);
  return v + __int_as_float(s);
}
__device__ __forceinline__ float row16_sum(float v) {
  v = dpp_add<0xB1>(v);   // quad_perm [1,0,3,2]
  v = dpp_add<0x4E>(v);   // quad_perm [2,3,0,1]
  v = dpp_add<0x141>(v);  // row_half_mirror
  v = dpp_add<0x140>(v);  // row_mirror
  return v;
}
__device__ __forceinline__ float rlane(float v, int l) {
  return __int_as_float(__builtin_amdgcn_readlane(__float_as_int(v), l));
}
__device__ __forceinline__ float wave_sum_dpp(float v) {
  const float r = row16_sum(v);
  return (rlane(r, 0) + rlane(r, 16)) + (rlane(r, 32) + rlane(r, 48));
}

// ---------------------------------------------------------------------------
// Xpre = X @ W   (16384 x 256) @ (256 x 256), f32
__global__ __launch_bounds__(256) void xpre_kernel(const float* __restrict__ X,
                                                   const float* __restrict__ W,
                                                   float* __restrict__ XP) {
  __shared__ __align__(16) float xs[32][D_];
  const int j = threadIdx.x;
  const int row0 = blockIdx.x * 32;
  for (int k = 0; k < 32; ++k)
    xs[k][j] = X[(size_t)(row0 + k) * D_ + j];
  __syncthreads();
  float acc[32];
#pragma unroll
  for (int k = 0; k < 32; ++k) acc[k] = 0.f;
  for (int d4 = 0; d4 < D_ / 4; ++d4) {
    const float w0 = W[(d4 * 4 + 0) * OUT_ + j];
    const float w1 = W[(d4 * 4 + 1) * OUT_ + j];
    const float w2 = W[(d4 * 4 + 2) * OUT_ + j];
    const float w3 = W[(d4 * 4 + 3) * OUT_ + j];
#pragma unroll
    for (int k = 0; k < 32; ++k) {
      const float4 x4 = *(const float4*)&xs[k][d4 * 4];
      acc[k] = fmaf(x4.x, w0, fmaf(x4.y, w1, fmaf(x4.z, w2, fmaf(x4.w, w3, acc[k]))));
    }
  }
  for (int k = 0; k < 32; ++k)
    XP[(size_t)(row0 + k) * OUT_ + j] = acc[k];
}

// ---------------------------------------------------------------------------
// attnK: attention weights + aggs for ALL (b,t). One wave per (b,t).
// walG[bt*256 + r*64 + c] = (ri[c]==r ? alpha[c] : 0).
__global__ __launch_bounds__(256) void attnK(const float* __restrict__ X,
                                             const int* __restrict__ Ri,
                                             const int* __restrict__ Ei,
                                             const float* __restrict__ Watt,
                                             float* __restrict__ walG,
                                             float* __restrict__ aggs) {
  const int wv = threadIdx.x >> 6;
  const int lane = threadIdx.x & 63;
  const size_t bt = (size_t)blockIdx.x * 4 + wv;
  const int r4 = lane >> 4, seg = lane & 15;

  float y = 0.f;
#pragma unroll
  for (int q = 0; q < 4; ++q) {
    const float4 wt = *(const float4*)&Watt[(r4 << 8) + (seg << 4) + (q << 2)];
    const float4 xv = *(const float4*)&X[bt * D_ + (seg << 4) + (q << 2)];
    y = fmaf(xv.x, wt.x, y);
    y = fmaf(xv.y, wt.y, y);
    y = fmaf(xv.z, wt.z, y);
    y = fmaf(xv.w, wt.w, y);
  }
  y = row16_sum(y);
  const float y0 = rlane(y, 0), y1 = rlane(y, 16);
  const float y2 = rlane(y, 32), y3 = rlane(y, 48);
  const int ric = Ri[bt * C_ + lane];
  const float eic = (float)Ei[bt * C_ + lane];
  float yv = (ric & 1) ? y1 : y0;
  const float yw = (ric & 1) ? y3 : y2;
  yv = (ric & 2) ? yw : yv;
  const float am = __expf(yv) * eic;  // EPS=1e-100 underflows in f32
  const float tot = wave_sum_dpp(am);
  const float alpha = __fdividef(am, tot);

  const float w0 = (ric == 0) ? alpha : 0.f;
  const float w1 = (ric == 1) ? alpha : 0.f;
  const float w2 = (ric == 2) ? alpha : 0.f;
  const float w3 = (ric == 3) ? alpha : 0.f;
  walG[bt * 256 + 0 * C_ + lane] = w0;
  walG[bt * 256 + 1 * C_ + lane] = w1;
  walG[bt * 256 + 2 * C_ + lane] = w2;
  walG[bt * 256 + 3 * C_ + lane] = w3;
  const float s0 = wave_sum_dpp(w0);
  const float s1 = wave_sum_dpp(w1);
  const float s2 = wave_sum_dpp(w2);
  const float s3 = wave_sum_dpp(w3);
  if (lane == 0) {
    float4 v = {s0, s1, s2, s3};
    *(float4*)&aggs[bt * R_] = v;
  }
}

// ---------------------------------------------------------------------------
// gruA: recurrent core. 256 threads (4 waves, 1/SIMD, 512-reg budget).
// Iterates ONLY over m=1 steps. 3 barriers/iter. LDS traffic minimized:
// broadcasts go through v_readlane (VALU) instead of the shared LDS pipe.
//  P1: prev[tid] = sum_c rl(walS,c) * mt[c][d]   (16 ds_read_b128 + RL/FMA)
//  P2: h2h[tid] via 1 lane-distributed ds_read_b128 of prev + 256 RL/FMA
//      (U fully register-resident, ureg[256]) + gates; reload S <- t_{k+2}
//  P3: m-update (LDS)
// m state TRANSPOSED+swizzled: (d,c) at word d*64 + (c^((d&7)<<2)).
__global__ __launch_bounds__(256, 1) void gruA(
    const int* __restrict__ M, const int* __restrict__ Eo,
    const int* __restrict__ Ro, const float* __restrict__ U,
    const float* __restrict__ Bv, const float* __restrict__ XP,
    const float* __restrict__ walG, float* __restrict__ hbuf) {
  __shared__ int sh_ro[2][C_];
  __shared__ int sh_eo[2][C_];
  __shared__ __align__(16) float sh_mt[C_ * RD_];
  __shared__ __align__(16) float sh_prev[OUT_];
  __shared__ __align__(16) float sh_hnew[OUT_];
  __shared__ int sh_tl[T_];
  __shared__ int sh_nT;

  const int tid = threadIdx.x;
  const int lane = tid & 63;
  const int w = tid >> 6;
  const int b = blockIdx.x;
  const size_t bt0 = (size_t)b * T_;

  // U column j=tid fully in registers (AGPR-backed at 1 wave/SIMD budget)
  float ureg[256];
#pragma unroll
  for (int i = 0; i < 256; ++i)
    ureg[i] = U[(size_t)i * OUT_ + tid];
  const float breg = Bv[tid];

  // zero m state
#pragma unroll
  for (int i = 0; i < 16; ++i) sh_mt[tid + (i << 8)] = 0.f;

  // tlist: indices of m=1 steps (wave 0, ballot prefix scan)
  if (tid < 64) {
    int base = 0;
    for (int ch = 0; ch < 8; ++ch) {
      const int mv = M[bt0 + (ch << 6) + lane];
      const unsigned long long mask = __ballot(mv != 0);
      if (mv) {
        const unsigned long long lt = ((lane == 63) ? ~0ull : ((1ull << (lane + 1)) - 1)) >> 1;
        sh_tl[base + __popcll(mask & lt)] = (ch << 6) + lane;
      }
      base += __popcll(mask);
    }
    if (lane == 0) sh_nT = base;
  }
  __syncthreads();
  const int nT = sh_nT;
  if (nT == 0) return;

  // parity register sets (per-thread): wal = wal[w][lane], xp = XP[.,tid]
  float walS0 = 0.f, xpS0 = 0.f, walS1 = 0.f, xpS1 = 0.f;
  int roS0 = 0, eoS0 = 0, roS1 = 0, eoS1 = 0;
  {
    const int t0 = sh_tl[0];
    walS0 = walG[(bt0 + t0) * 256 + tid];
    xpS0 = XP[(bt0 + t0) * 256 + tid];
    if (tid < 64) {
      roS0 = Ro[(bt0 + t0) * C_ + tid];
      eoS0 = Eo[(bt0 + t0) * C_ + tid];
    }
  }
  if (nT > 1) {
    const int t1 = sh_tl[1];
    walS1 = walG[(bt0 + t1) * 256 + tid];
    xpS1 = XP[(bt0 + t1) * 256 + tid];
    if (tid < 64) {
      roS1 = Ro[(bt0 + t1) * C_ + tid];
      eoS1 = Eo[(bt0 + t1) * C_ + tid];
    }
  }

  const int d = lane;
  const int s = (d & 7) << 2;
  const int mbase = d << 6;

  // one m=1 step; S-set is consumed then reloaded in place for t_{k+2}
  auto do_step = [&](int k, float& walS, float& xpS, int& roS, int& eoS) {
    const int cur = k & 1;
    const size_t bt = bt0 + sh_tl[k];

    // ---- P1: ro/eo -> LDS (wave0) + prev GEMV (wal via readlane) ----
    if (tid < 64) {
      sh_ro[cur][tid] = roS;
      sh_eo[cur][tid] = eoS;
    }
    float a0 = 0.f, a1 = 0.f, a2 = 0.f, a3 = 0.f;
#pragma unroll
    for (int c4 = 0; c4 < 16; ++c4) {
      const int c0 = c4 << 2;
      const float4 mv = *(const float4*)&sh_mt[mbase + (c0 ^ s)];
      a0 = fmaf(rlane(walS, c0 + 0), mv.x, a0);
      a1 = fmaf(rlane(walS, c0 + 1), mv.y, a1);
      a2 = fmaf(rlane(walS, c0 + 2), mv.z, a2);
      a3 = fmaf(rlane(walS, c0 + 3), mv.w, a3);
    }
    const float prevreg = (a0 + a1) + (a2 + a3);
    sh_prev[tid] = prevreg;
    bar_lds();

    // ---- P2: h2h via 1 lane-distributed read + readlane/FMA; gates ----
    const float4 pv = *(const float4*)&sh_prev[lane << 2];  // lane l: prev[4l..]
    float s0 = 0.f, s1 = 0.f, s2 = 0.f, s3 = 0.f;
#pragma unroll
    for (int i = 0; i < 64; ++i) {
      s0 = fmaf(rlane(pv.x, i), ureg[(i << 2) + 0], s0);
      s1 = fmaf(rlane(pv.y, i), ureg[(i << 2) + 1], s1);
      s2 = fmaf(rlane(pv.z, i), ureg[(i << 2) + 2], s2);
      s3 = fmaf(rlane(pv.w, i), ureg[(i << 2) + 3], s3);
    }
    const float h2h = (s0 + s1) + (s2 + s3);
    const float g1 = xpS + h2h + breg;
    const float rg = 1.f / (1.f + __expf(-g1));
    const float targ = xpS + rg * h2h + breg;
    const float e2 = __expf(2.f * targ);
    const float ht = 1.f - 2.f / (e2 + 1.f);  // tanh
    const float hn = (1.f - rg) * prevreg + rg * ht;
    sh_hnew[tid] = hn;
    hbuf[bt * OUT_ + tid] = hn;
    // reload this parity set for t_{k+2} (all consumers above are done)
    if (k + 2 < nT) {
      const int t2 = sh_tl[k + 2];
      walS = walG[(bt0 + t2) * 256 + tid];
      xpS = XP[(bt0 + t2) * 256 + tid];
      if (tid < 64) {
        roS = Ro[(bt0 + t2) * C_ + tid];
        eoS = Eo[(bt0 + t2) * C_ + tid];
      }
    }
    bar_lds();

    // ---- P3: m-update (16 elems/thread: c = w*16..+15 at row d) ----
#pragma unroll
    for (int q = 0; q < 4; ++q) {
      const int c0 = (w << 4) + (q << 2);
      float4 mm = *(float4*)&sh_mt[mbase + (c0 ^ s)];
      const float h0 = sh_hnew[(sh_ro[cur][c0 + 0] << 6) + d];
      const float h1 = sh_hnew[(sh_ro[cur][c0 + 1] << 6) + d];
      const float h2 = sh_hnew[(sh_ro[cur][c0 + 2] << 6) + d];
      const float h3 = sh_hnew[(sh_ro[cur][c0 + 3] << 6) + d];
      mm.x = sh_eo[cur][c0 + 0] ? h0 : mm.x;
      mm.y = sh_eo[cur][c0 + 1] ? h1 : mm.y;
      mm.z = sh_eo[cur][c0 + 2] ? h2 : mm.z;
      mm.w = sh_eo[cur][c0 + 3] ? h3 : mm.w;
      *(float4*)&sh_mt[mbase + (c0 ^ s)] = mm;
    }
    bar_lds();
  };

  for (int k = 0; k < nT; k += 2) {
    do_step(k, walS0, xpS0, roS0, eoS0);
    if (k + 1 < nT) do_step(k + 1, walS1, xpS1, roS1, eoS1);
  }
}

// ---------------------------------------------------------------------------
// memsB: mems[b,t,c,:] = hbuf(tau)[ro(tau,c)*64+:], tau = last step<=t with
// M&Eo, else 0. One block per (b,c).
__global__ __launch_bounds__(512) void memsB(const int* __restrict__ M,
                                             const int* __restrict__ Eo,
                                             const int* __restrict__ Ro,
                                             const float* __restrict__ hbuf,
                                             float* __restrict__ mems) {
  __shared__ int lastA[T_];
  const int tid = threadIdx.x;
  const int b = blockIdx.x >> 6;
  const int c = blockIdx.x & 63;
  const size_t bt0 = (size_t)b * T_;
  {
    const int upd = M[bt0 + tid] & Eo[(bt0 + tid) * C_ + c];
    lastA[tid] = upd ? tid : -1;
  }
  __syncthreads();
  for (int off = 1; off < T_; off <<= 1) {
    const int u = (tid >= off) ? lastA[tid - off] : -1;
    const int v = lastA[tid];
    __syncthreads();
    lastA[tid] = (u > v) ? u : v;
    __syncthreads();
  }
  const int d = tid & 63;
  const int t8 = tid >> 6;
  for (int tt = 0; tt < 64; ++tt) {
    const int t = (tt << 3) + t8;
    const int tau = lastA[t];
    float v = 0.f;
    if (tau >= 0) {
      const int rc = Ro[(bt0 + tau) * C_ + c];
      v = hbuf[(bt0 + tau) * OUT_ + (rc << 6) + d];
    }
    mems[((bt0 + t) * C_ + c) * RD_ + d] = v;
  }
}

// ---------------------------------------------------------------------------
// outsC: outs[b,t,:] = hbuf(tauM), tauM = last M=1 step <= t, else 0.
// In place on hbuf/outs, descending t.
__global__ __launch_bounds__(512) void outsC(const int* __restrict__ M,
                                             float* __restrict__ outs) {
  __shared__ int lastM[T_];
  const int tid = threadIdx.x;
  const int b = blockIdx.x;
  const size_t bt0 = (size_t)b * T_;
  lastM[tid] = M[bt0 + tid] ? tid : -1;
  __syncthreads();
  for (int off = 1; off < T_; off <<= 1) {
    const int u = (tid >= off) ? lastM[tid - off] : -1;
    const int v = lastM[tid];
    __syncthreads();
    lastM[tid] = (u > v) ? u : v;
    __syncthreads();
  }
  const int j = tid & 255;
  const int th = tid >> 8;
  for (int k = 0; k < 256; ++k) {
    const int t = 511 - (k << 1) - th;
    const int tau = lastM[t];
    const float v = (tau >= 0) ? outs[(bt0 + tau) * OUT_ + j] : 0.f;
    __syncthreads();
    outs[(bt0 + t) * OUT_ + j] = v;
  }
}

// ---------------------------------------------------------------------------
extern "C" void kernel_launch(void* const* d_in, const int* in_sizes, int n_in,
                              void* d_out, int out_size, void* d_ws, size_t ws_size,
                              hipStream_t stream) {
  const float* X = (const float*)d_in[0];
  const int* M = (const int*)d_in[1];
  const int* Ei = (const int*)d_in[2];
  const int* Eo = (const int*)d_in[3];
  const int* Ri = (const int*)d_in[4];
  const int* Ro = (const int*)d_in[5];
  const float* W = (const float*)d_in[6];
  const float* U = (const float*)d_in[7];
  const float* Bv = (const float*)d_in[8];
  const float* Watt = (const float*)d_in[9];

  float* outs = (float*)d_out;
  float* mems = outs + (size_t)B_ * T_ * OUT_;
  float* aggs = mems + (size_t)B_ * T_ * C_ * RD_;
  float* XP = (float*)d_ws;   // 16.8 MB scratch
  float* hbuf = outs;         // hnew history aliases outs (outsC finalizes)
  float* walG = mems;         // alpha scratch aliases mems (memsB overwrites)

  xpre_kernel<<<dim3(B_ * T_ / 32), dim3(256), 0, stream>>>(X, W, XP);
  attnK<<<dim3(B_ * T_ / 4), dim3(256), 0, stream>>>(X, Ri, Ei, Watt, walG, aggs);
  gruA<<<dim3(B_), dim3(256), 0, stream>>>(M, Eo, Ro, U, Bv, XP, walG, hbuf);
  memsB<<<dim3(B_ * C_), dim3(512), 0, stream>>>(M, Eo, Ro, hbuf, mems);
  outsC<<<dim3(B_), dim3(512), 0, stream>>>(M, outs);
}

// Round 10
// 1083.059 us; speedup vs baseline: 2.3698x; 1.1037x over previous
//
#include <hip/hip_runtime.h>

#define B_   32
#define T_   512
#define D_   256
#define C_   64
#define R_   4
#define RD_  64
#define OUT_ 256

// ---------------------------------------------------------------------------
__device__ __forceinline__ void bar_lds() {
  asm volatile("s_waitcnt lgkmcnt(0)" ::: "memory");
  __builtin_amdgcn_s_barrier();
  asm volatile("" ::: "memory");
}

// ---- DPP-based wave reductions (VALU pipe) ---------------------------------
template <int CTRL>
__device__ __forceinline__ float dpp_add(float v) {
  int s = __builtin_amdgcn_update_dpp(0, __float_as_int(v), CTRL, 0xF, 0xF, true);
  return v + __int_as_float(s);
}
__device__ __forceinline__ float row16_sum(float v) {
  v = dpp_add<0xB1>(v);   // quad_perm [1,0,3,2]
  v = dpp_add<0x4E>(v);   // quad_perm [2,3,0,1]
  v = dpp_add<0x141>(v);  // row_half_mirror
  v = dpp_add<0x140>(v);  // row_mirror
  return v;
}
__device__ __forceinline__ float rlane(float v, int l) {
  return __int_as_float(__builtin_amdgcn_readlane(__float_as_int(v), l));
}
__device__ __forceinline__ int rlane_i(int v, int l) {
  return __builtin_amdgcn_readlane(v, l);
}
__device__ __forceinline__ float wave_sum_dpp(float v) {
  const float r = row16_sum(v);
  return (rlane(r, 0) + rlane(r, 16)) + (rlane(r, 32) + rlane(r, 48));
}

// ---------------------------------------------------------------------------
// Xpre = X @ W   (16384 x 256) @ (256 x 256), f32
__global__ __launch_bounds__(256) void xpre_kernel(const float* __restrict__ X,
                                                   const float* __restrict__ W,
                                                   float* __restrict__ XP) {
  __shared__ __align__(16) float xs[32][D_];
  const int j = threadIdx.x;
  const int row0 = blockIdx.x * 32;
  for (int k = 0; k < 32; ++k)
    xs[k][j] = X[(size_t)(row0 + k) * D_ + j];
  __syncthreads();
  float acc[32];
#pragma unroll
  for (int k = 0; k < 32; ++k) acc[k] = 0.f;
  for (int d4 = 0; d4 < D_ / 4; ++d4) {
    const float w0 = W[(d4 * 4 + 0) * OUT_ + j];
    const float w1 = W[(d4 * 4 + 1) * OUT_ + j];
    const float w2 = W[(d4 * 4 + 2) * OUT_ + j];
    const float w3 = W[(d4 * 4 + 3) * OUT_ + j];
#pragma unroll
    for (int k = 0; k < 32; ++k) {
      const float4 x4 = *(const float4*)&xs[k][d4 * 4];
      acc[k] = fmaf(x4.x, w0, fmaf(x4.y, w1, fmaf(x4.z, w2, fmaf(x4.w, w3, acc[k]))));
    }
  }
  for (int k = 0; k < 32; ++k)
    XP[(size_t)(row0 + k) * OUT_ + j] = acc[k];
}

// ---------------------------------------------------------------------------
// attnK: attention weights + aggs for ALL (b,t). One wave per (b,t).
// walG[bt*256 + r*64 + c] = (ri[c]==r ? alpha[c] : 0).
__global__ __launch_bounds__(256) void attnK(const float* __restrict__ X,
                                             const int* __restrict__ Ri,
                                             const int* __restrict__ Ei,
                                             const float* __restrict__ Watt,
                                             float* __restrict__ walG,
                                             float* __restrict__ aggs) {
  const int wv = threadIdx.x >> 6;
  const int lane = threadIdx.x & 63;
  const size_t bt = (size_t)blockIdx.x * 4 + wv;
  const int r4 = lane >> 4, seg = lane & 15;

  float y = 0.f;
#pragma unroll
  for (int q = 0; q < 4; ++q) {
    const float4 wt = *(const float4*)&Watt[(r4 << 8) + (seg << 4) + (q << 2)];
    const float4 xv = *(const float4*)&X[bt * D_ + (seg << 4) + (q << 2)];
    y = fmaf(xv.x, wt.x, y);
    y = fmaf(xv.y, wt.y, y);
    y = fmaf(xv.z, wt.z, y);
    y = fmaf(xv.w, wt.w, y);
  }
  y = row16_sum(y);
  const float y0 = rlane(y, 0), y1 = rlane(y, 16);
  const float y2 = rlane(y, 32), y3 = rlane(y, 48);
  const int ric = Ri[bt * C_ + lane];
  const float eic = (float)Ei[bt * C_ + lane];
  float yv = (ric & 1) ? y1 : y0;
  const float yw = (ric & 1) ? y3 : y2;
  yv = (ric & 2) ? yw : yv;
  const float am = __expf(yv) * eic;  // EPS=1e-100 underflows in f32
  const float tot = wave_sum_dpp(am);
  const float alpha = __fdividef(am, tot);

  const float w0 = (ric == 0) ? alpha : 0.f;
  const float w1 = (ric == 1) ? alpha : 0.f;
  const float w2 = (ric == 2) ? alpha : 0.f;
  const float w3 = (ric == 3) ? alpha : 0.f;
  walG[bt * 256 + 0 * C_ + lane] = w0;
  walG[bt * 256 + 1 * C_ + lane] = w1;
  walG[bt * 256 + 2 * C_ + lane] = w2;
  walG[bt * 256 + 3 * C_ + lane] = w3;
  const float s0 = wave_sum_dpp(w0);
  const float s1 = wave_sum_dpp(w1);
  const float s2 = wave_sum_dpp(w2);
  const float s3 = wave_sum_dpp(w3);
  if (lane == 0) {
    float4 v = {s0, s1, s2, s3};
    *(float4*)&aggs[bt * R_] = v;
  }
}

// ---------------------------------------------------------------------------
// gruA: recurrent core. 256 threads (4 waves, 1/SIMD, 512-reg budget).
// Iterates ONLY over m=1 steps. 2 barriers/iter.
// m state lives in REGISTERS: thread (w,lane) holds mtreg[q] = mt[16w+q][lane].
// U column j=tid in ureg[256] (AGPR-backed). No mt LDS arrays at all.
//  A: per-wave prev partials (wal via in-wave readlane) -> shp[w][r][lane]
//  B: pv = cross-wave sum of shp; h2h via readlane/FMA; gates; hnew; prefetch
//  C: mtreg select-update (ro/eo via in-wave readlane; hnew via 4 b32 reads)
__global__ __launch_bounds__(256, 1) void gruA(
    const int* __restrict__ M, const int* __restrict__ Eo,
    const int* __restrict__ Ro, const float* __restrict__ U,
    const float* __restrict__ Bv, const float* __restrict__ XP,
    const float* __restrict__ walG, float* __restrict__ hbuf) {
  __shared__ __align__(16) float shp[4][256];   // [w][r*64+d] prev partials
  __shared__ __align__(16) float sh_hnew[OUT_];
  __shared__ int sh_tl[T_];
  __shared__ int sh_nT;

  const int tid = threadIdx.x;
  const int lane = tid & 63;
  const int w = tid >> 6;
  const int b = blockIdx.x;
  const size_t bt0 = (size_t)b * T_;

  // U column j=tid fully in registers
  float ureg[256];
#pragma unroll
  for (int i = 0; i < 256; ++i)
    ureg[i] = U[(size_t)i * OUT_ + tid];
  const float breg = Bv[tid];

  // m state: mtreg[q] = mt[16w+q][lane], init 0
  float mtreg[16];
#pragma unroll
  for (int q = 0; q < 16; ++q) mtreg[q] = 0.f;

  // tlist: indices of m=1 steps (wave 0, ballot prefix scan)
  if (tid < 64) {
    int base = 0;
    for (int ch = 0; ch < 8; ++ch) {
      const int mv = M[bt0 + (ch << 6) + lane];
      const unsigned long long mask = __ballot(mv != 0);
      if (mv) {
        const unsigned long long lt = ((lane == 63) ? ~0ull : ((1ull << (lane + 1)) - 1)) >> 1;
        sh_tl[base + __popcll(mask & lt)] = (ch << 6) + lane;
      }
      base += __popcll(mask);
    }
    if (lane == 0) sh_nT = base;
  }
  __syncthreads();
  const int nT = sh_nT;
  if (nT == 0) return;

  // parity register sets:
  //  walS: wal[r=tid&3][c = 16w + (lane>>2)]   (in-wave readlane at 4q+r)
  //  xpS : XP[., tid]
  //  roeoS: Ro | (Eo<<8) at c = 16w + (lane&15) (in-wave readlane at q)
  const int cwal = (w << 4) + (lane >> 2);
  const int croeo = (w << 4) + (lane & 15);
  float walS0 = 0.f, xpS0 = 0.f, walS1 = 0.f, xpS1 = 0.f;
  int roeoS0 = 0, roeoS1 = 0;
  {
    const int t0 = sh_tl[0];
    walS0 = walG[(bt0 + t0) * 256 + ((tid & 3) << 6) + cwal];
    xpS0 = XP[(bt0 + t0) * 256 + tid];
    roeoS0 = Ro[(bt0 + t0) * C_ + croeo] | (Eo[(bt0 + t0) * C_ + croeo] << 8);
  }
  if (nT > 1) {
    const int t1 = sh_tl[1];
    walS1 = walG[(bt0 + t1) * 256 + ((tid & 3) << 6) + cwal];
    xpS1 = XP[(bt0 + t1) * 256 + tid];
    roeoS1 = Ro[(bt0 + t1) * C_ + croeo] | (Eo[(bt0 + t1) * C_ + croeo] << 8);
  }

  auto do_step = [&](int k, float& walS, float& xpS, int& roeoS) {
    const size_t bt = bt0 + sh_tl[k];
    const int roeoCur = roeoS;  // consume before the k+2 reload overwrites

    // ---- A: prev partials from mtreg (pure VALU) -> shp ----
    float a0 = 0.f, a1 = 0.f, a2 = 0.f, a3 = 0.f;
#pragma unroll
    for (int q = 0; q < 16; ++q) {
      const float mq = mtreg[q];
      a0 = fmaf(rlane(walS, 4 * q + 0), mq, a0);
      a1 = fmaf(rlane(walS, 4 * q + 1), mq, a1);
      a2 = fmaf(rlane(walS, 4 * q + 2), mq, a2);
      a3 = fmaf(rlane(walS, 4 * q + 3), mq, a3);
    }
    shp[w][0 * 64 + lane] = a0;
    shp[w][1 * 64 + lane] = a1;
    shp[w][2 * 64 + lane] = a2;
    shp[w][3 * 64 + lane] = a3;
    bar_lds();

    // ---- B: pv (lane l holds prev[4l..4l+3]); h2h; gates; hnew; reload ----
    const int pbase = ((lane >> 4) << 6) + ((lane & 15) << 2);  // r*64 + 4*(l&15)
    const float4 p0 = *(const float4*)&shp[0][pbase];
    const float4 p1 = *(const float4*)&shp[1][pbase];
    const float4 p2 = *(const float4*)&shp[2][pbase];
    const float4 p3 = *(const float4*)&shp[3][pbase];
    float4 pv;
    pv.x = (p0.x + p1.x) + (p2.x + p3.x);
    pv.y = (p0.y + p1.y) + (p2.y + p3.y);
    pv.z = (p0.z + p1.z) + (p2.z + p3.z);
    pv.w = (p0.w + p1.w) + (p2.w + p3.w);
    // own prev[tid] (banks = tid&63 -> 2-way, free)
    const float prevreg = ((shp[0][tid & 255] + shp[1][tid & 255]) +
                           (shp[2][tid & 255] + shp[3][tid & 255]));
    float s0 = 0.f, s1 = 0.f, s2 = 0.f, s3 = 0.f;
#pragma unroll
    for (int i = 0; i < 64; ++i) {
      s0 = fmaf(rlane(pv.x, i), ureg[(i << 2) + 0], s0);
      s1 = fmaf(rlane(pv.y, i), ureg[(i << 2) + 1], s1);
      s2 = fmaf(rlane(pv.z, i), ureg[(i << 2) + 2], s2);
      s3 = fmaf(rlane(pv.w, i), ureg[(i << 2) + 3], s3);
    }
    const float h2h = (s0 + s1) + (s2 + s3);
    const float g1 = xpS + h2h + breg;
    const float rg = 1.f / (1.f + __expf(-g1));
    const float targ = xpS + rg * h2h + breg;
    const float e2 = __expf(2.f * targ);
    const float ht = 1.f - 2.f / (e2 + 1.f);  // tanh
    const float hn = (1.f - rg) * prevreg + rg * ht;
    sh_hnew[tid] = hn;
    hbuf[bt * OUT_ + tid] = hn;
    // reload this parity set for t_{k+2} (walS/xpS consumed above)
    if (k + 2 < nT) {
      const int t2 = sh_tl[k + 2];
      walS = walG[(bt0 + t2) * 256 + ((tid & 3) << 6) + cwal];
      xpS = XP[(bt0 + t2) * 256 + tid];
      roeoS = Ro[(bt0 + t2) * C_ + croeo] | (Eo[(bt0 + t2) * C_ + croeo] << 8);
    }
    bar_lds();

    // ---- C: mtreg select-update (registers only; hnew via 4 b32 reads) ----
    const float h0 = sh_hnew[0 * 64 + lane];
    const float h1 = sh_hnew[1 * 64 + lane];
    const float h2 = sh_hnew[2 * 64 + lane];
    const float h3 = sh_hnew[3 * 64 + lane];
#pragma unroll
    for (int q = 0; q < 16; ++q) {
      const int re = rlane_i(roeoCur, q);   // uniform: ro | eo<<8
      const int ro = re & 0xFF;
      const float ha = (ro & 1) ? h1 : h0;
      const float hb = (ro & 1) ? h3 : h2;
      const float hs = (ro & 2) ? hb : ha;
      mtreg[q] = (re & 0x100) ? hs : mtreg[q];
    }
    // falls through into next iteration's A (shp WAR-safe: last read pre-bar)
  };

  for (int k = 0; k < nT; k += 2) {
    do_step(k, walS0, xpS0, roeoS0);
    if (k + 1 < nT) do_step(k + 1, walS1, xpS1, roeoS1);
  }
}

// ---------------------------------------------------------------------------
// memsB: mems[b,t,c,:] = hbuf(tau)[ro(tau,c)*64+:], tau = last step<=t with
// M&Eo, else 0. One block per (b,c).
__global__ __launch_bounds__(512) void memsB(const int* __restrict__ M,
                                             const int* __restrict__ Eo,
                                             const int* __restrict__ Ro,
                                             const float* __restrict__ hbuf,
                                             float* __restrict__ mems) {
  __shared__ int lastA[T_];
  const int tid = threadIdx.x;
  const int b = blockIdx.x >> 6;
  const int c = blockIdx.x & 63;
  const size_t bt0 = (size_t)b * T_;
  {
    const int upd = M[bt0 + tid] & Eo[(bt0 + tid) * C_ + c];
    lastA[tid] = upd ? tid : -1;
  }
  __syncthreads();
  for (int off = 1; off < T_; off <<= 1) {
    const int u = (tid >= off) ? lastA[tid - off] : -1;
    const int v = lastA[tid];
    __syncthreads();
    lastA[tid] = (u > v) ? u : v;
    __syncthreads();
  }
  const int d = tid & 63;
  const int t8 = tid >> 6;
  for (int tt = 0; tt < 64; ++tt) {
    const int t = (tt << 3) + t8;
    const int tau = lastA[t];
    float v = 0.f;
    if (tau >= 0) {
      const int rc = Ro[(bt0 + tau) * C_ + c];
      v = hbuf[(bt0 + tau) * OUT_ + (rc << 6) + d];
    }
    mems[((bt0 + t) * C_ + c) * RD_ + d] = v;
  }
}

// ---------------------------------------------------------------------------
// outsC: outs[b,t,:] = hbuf(tauM), tauM = last M=1 step <= t, else 0.
// In place on hbuf/outs, descending t.
__global__ __launch_bounds__(512) void outsC(const int* __restrict__ M,
                                             float* __restrict__ outs) {
  __shared__ int lastM[T_];
  const int tid = threadIdx.x;
  const int b = blockIdx.x;
  const size_t bt0 = (size_t)b * T_;
  lastM[tid] = M[bt0 + tid] ? tid : -1;
  __syncthreads();
  for (int off = 1; off < T_; off <<= 1) {
    const int u = (tid >= off) ? lastM[tid - off] : -1;
    const int v = lastM[tid];
    __syncthreads();
    lastM[tid] = (u > v) ? u : v;
    __syncthreads();
  }
  const int j = tid & 255;
  const int th = tid >> 8;
  for (int k = 0; k < 256; ++k) {
    const int t = 511 - (k << 1) - th;
    const int tau = lastM[t];
    const float v = (tau >= 0) ? outs[(bt0 + tau) * OUT_ + j] : 0.f;
    __syncthreads();
    outs[(bt0 + t) * OUT_ + j] = v;
  }
}

// ---------------------------------------------------------------------------
extern "C" void kernel_launch(void* const* d_in, const int* in_sizes, int n_in,
                              void* d_out, int out_size, void* d_ws, size_t ws_size,
                              hipStream_t stream) {
  const float* X = (const float*)d_in[0];
  const int* M = (const int*)d_in[1];
  const int* Ei = (const int*)d_in[2];
  const int* Eo = (const int*)d_in[3];
  const int* Ri = (const int*)d_in[4];
  const int* Ro = (const int*)d_in[5];
  const float* W = (const float*)d_in[6];
  const float* U = (const float*)d_in[7];
  const float* Bv = (const float*)d_in[8];
  const float* Watt = (const float*)d_in[9];

  float* outs = (float*)d_out;
  float* mems = outs + (size_t)B_ * T_ * OUT_;
  float* aggs = mems + (size_t)B_ * T_ * C_ * RD_;
  float* XP = (float*)d_ws;   // 16.8 MB scratch
  float* hbuf = outs;         // hnew history aliases outs (outsC finalizes)
  float* walG = mems;         // alpha scratch aliases mems (memsB overwrites)

  xpre_kernel<<<dim3(B_ * T_ / 32), dim3(256), 0, stream>>>(X, W, XP);
  attnK<<<dim3(B_ * T_ / 4), dim3(256), 0, stream>>>(X, Ri, Ei, Watt, walG, aggs);
  gruA<<<dim3(B_), dim3(256), 0, stream>>>(M, Eo, Ro, U, Bv, XP, walG, hbuf);
  memsB<<<dim3(B_ * C_), dim3(512), 0, stream>>>(M, Eo, Ro, hbuf, mems);
  outsC<<<dim3(B_), dim3(512), 0, stream>>>(M, outs);
}

// Round 11
// 878.330 us; speedup vs baseline: 2.9221x; 1.2331x over previous
//
#include <hip/hip_runtime.h>

#define B_   32
#define T_   512
#define D_   256
#define C_   64
#define R_   4
#define RD_  64
#define OUT_ 256

// ---------------------------------------------------------------------------
__device__ __forceinline__ void bar_lds() {
  asm volatile("s_waitcnt lgkmcnt(0)" ::: "memory");
  __builtin_amdgcn_s_barrier();
  asm volatile("" ::: "memory");
}

// ---- DPP-based wave reductions (VALU pipe) ---------------------------------
template <int CTRL>
__device__ __forceinline__ float dpp_add(float v) {
  int s = __builtin_amdgcn_update_dpp(0, __float_as_int(v), CTRL, 0xF, 0xF, true);
  return v + __int_as_float(s);
}
__device__ __forceinline__ float row16_sum(float v) {
  v = dpp_add<0xB1>(v);   // quad_perm [1,0,3,2]
  v = dpp_add<0x4E>(v);   // quad_perm [2,3,0,1]
  v = dpp_add<0x141>(v);  // row_half_mirror
  v = dpp_add<0x140>(v);  // row_mirror
  return v;
}
__device__ __forceinline__ float rlane(float v, int l) {
  return __int_as_float(__builtin_amdgcn_readlane(__float_as_int(v), l));
}
__device__ __forceinline__ int rlane_i(int v, int l) {
  return __builtin_amdgcn_readlane(v, l);
}
__device__ __forceinline__ float wave_sum_dpp(float v) {
  const float r = row16_sum(v);
  return (rlane(r, 0) + rlane(r, 16)) + (rlane(r, 32) + rlane(r, 48));
}

// ---------------------------------------------------------------------------
// Xpre = X @ W   (16384 x 256) @ (256 x 256), f32
__global__ __launch_bounds__(256) void xpre_kernel(const float* __restrict__ X,
                                                   const float* __restrict__ W,
                                                   float* __restrict__ XP) {
  __shared__ __align__(16) float xs[32][D_];
  const int j = threadIdx.x;
  const int row0 = blockIdx.x * 32;
  for (int k = 0; k < 32; ++k)
    xs[k][j] = X[(size_t)(row0 + k) * D_ + j];
  __syncthreads();
  float acc[32];
#pragma unroll
  for (int k = 0; k < 32; ++k) acc[k] = 0.f;
  for (int d4 = 0; d4 < D_ / 4; ++d4) {
    const float w0 = W[(d4 * 4 + 0) * OUT_ + j];
    const float w1 = W[(d4 * 4 + 1) * OUT_ + j];
    const float w2 = W[(d4 * 4 + 2) * OUT_ + j];
    const float w3 = W[(d4 * 4 + 3) * OUT_ + j];
#pragma unroll
    for (int k = 0; k < 32; ++k) {
      const float4 x4 = *(const float4*)&xs[k][d4 * 4];
      acc[k] = fmaf(x4.x, w0, fmaf(x4.y, w1, fmaf(x4.z, w2, fmaf(x4.w, w3, acc[k]))));
    }
  }
  for (int k = 0; k < 32; ++k)
    XP[(size_t)(row0 + k) * OUT_ + j] = acc[k];
}

// ---------------------------------------------------------------------------
// attnK: attention weights + aggs for ALL (b,t). One wave per (b,t).
// walG[bt*256 + r*64 + c] = (ri[c]==r ? alpha[c] : 0).
__global__ __launch_bounds__(256) void attnK(const float* __restrict__ X,
                                             const int* __restrict__ Ri,
                                             const int* __restrict__ Ei,
                                             const float* __restrict__ Watt,
                                             float* __restrict__ walG,
                                             float* __restrict__ aggs) {
  const int wv = threadIdx.x >> 6;
  const int lane = threadIdx.x & 63;
  const size_t bt = (size_t)blockIdx.x * 4 + wv;
  const int r4 = lane >> 4, seg = lane & 15;

  float y = 0.f;
#pragma unroll
  for (int q = 0; q < 4; ++q) {
    const float4 wt = *(const float4*)&Watt[(r4 << 8) + (seg << 4) + (q << 2)];
    const float4 xv = *(const float4*)&X[bt * D_ + (seg << 4) + (q << 2)];
    y = fmaf(xv.x, wt.x, y);
    y = fmaf(xv.y, wt.y, y);
    y = fmaf(xv.z, wt.z, y);
    y = fmaf(xv.w, wt.w, y);
  }
  y = row16_sum(y);
  const float y0 = rlane(y, 0), y1 = rlane(y, 16);
  const float y2 = rlane(y, 32), y3 = rlane(y, 48);
  const int ric = Ri[bt * C_ + lane];
  const float eic = (float)Ei[bt * C_ + lane];
  float yv = (ric & 1) ? y1 : y0;
  const float yw = (ric & 1) ? y3 : y2;
  yv = (ric & 2) ? yw : yv;
  const float am = __expf(yv) * eic;  // EPS=1e-100 underflows in f32
  const float tot = wave_sum_dpp(am);
  const float alpha = __fdividef(am, tot);

  const float w0 = (ric == 0) ? alpha : 0.f;
  const float w1 = (ric == 1) ? alpha : 0.f;
  const float w2 = (ric == 2) ? alpha : 0.f;
  const float w3 = (ric == 3) ? alpha : 0.f;
  walG[bt * 256 + 0 * C_ + lane] = w0;
  walG[bt * 256 + 1 * C_ + lane] = w1;
  walG[bt * 256 + 2 * C_ + lane] = w2;
  walG[bt * 256 + 3 * C_ + lane] = w3;
  const float s0 = wave_sum_dpp(w0);
  const float s1 = wave_sum_dpp(w1);
  const float s2 = wave_sum_dpp(w2);
  const float s3 = wave_sum_dpp(w3);
  if (lane == 0) {
    float4 v = {s0, s1, s2, s3};
    *(float4*)&aggs[bt * R_] = v;
  }
}

// ---------------------------------------------------------------------------
// gruA: recurrent core. 256 threads (4 waves, 1/SIMD, 512-reg budget).
// Iterates ONLY over m=1 steps. 3 barriers/iter.
// m state in registers: mtreg[q] = mt[16w+q][lane].
// U relaid for K-split h2h: thread t=64w+l holds ureg[jj*64+i] =
//   U[64w+i][jj*64+l]  (its wave's K-quarter for 4 outputs).
//  A : per-wave prev partials (wal via readlane, mtreg) -> shp[w][r*64+d]
//  B1: prevX = prev[tid] (4 b32); partials p[jj] over K-quarter via
//      64 RL (1:4 RL:FMA) -> pBred[w][jj*64+l]
//  B2: h2h = sum_w pBred; gates (prevX in reg); sh_hnew + hbuf; reloads
//  C : mtreg select-update (ro/eo via readlane; hnew via 4 b32 reads)
__global__ __launch_bounds__(256, 1) void gruA(
    const int* __restrict__ M, const int* __restrict__ Eo,
    const int* __restrict__ Ro, const float* __restrict__ U,
    const float* __restrict__ Bv, const float* __restrict__ XP,
    const float* __restrict__ walG, float* __restrict__ hbuf) {
  __shared__ __align__(16) float shp[4][256];    // [aw][r*64+d] prev partials
  __shared__ __align__(16) float pBred[4][256];  // [kw][j] h2h partials
  __shared__ __align__(16) float sh_hnew[OUT_];
  __shared__ int sh_tl[T_];
  __shared__ int sh_nT;

  const int tid = threadIdx.x;
  const int lane = tid & 63;
  const int w = tid >> 6;
  const int b = blockIdx.x;
  const size_t bt0 = (size_t)b * T_;

  // U slice: ureg[jj*64+i] = U[64w+i][jj*64+lane]
  float ureg[256];
#pragma unroll
  for (int jj = 0; jj < 4; ++jj)
#pragma unroll
    for (int i = 0; i < 64; ++i)
      ureg[(jj << 6) + i] = U[(size_t)((w << 6) + i) * OUT_ + (jj << 6) + lane];
  const float breg = Bv[tid];

  // m state: mtreg[q] = mt[16w+q][lane], init 0
  float mtreg[16];
#pragma unroll
  for (int q = 0; q < 16; ++q) mtreg[q] = 0.f;

  // tlist: indices of m=1 steps (wave 0, ballot prefix scan)
  if (tid < 64) {
    int base = 0;
    for (int ch = 0; ch < 8; ++ch) {
      const int mv = M[bt0 + (ch << 6) + lane];
      const unsigned long long mask = __ballot(mv != 0);
      if (mv) {
        const unsigned long long lt = ((lane == 63) ? ~0ull : ((1ull << (lane + 1)) - 1)) >> 1;
        sh_tl[base + __popcll(mask & lt)] = (ch << 6) + lane;
      }
      base += __popcll(mask);
    }
    if (lane == 0) sh_nT = base;
  }
  __syncthreads();
  const int nT = sh_nT;
  if (nT == 0) return;

  // parity register sets:
  //  walS : wal[r=tid&3][c = 16w + (lane>>2)]  (A: readlane at 4q+r)
  //  xpS  : XP[., tid]
  //  roeoS: Ro | (Eo<<8) at c = 16w + (lane&15) (C: readlane at q)
  const int cwal = (w << 4) + (lane >> 2);
  const int croeo = (w << 4) + (lane & 15);
  float walS0 = 0.f, xpS0 = 0.f, walS1 = 0.f, xpS1 = 0.f;
  int roeoS0 = 0, roeoS1 = 0;
  {
    const int t0 = sh_tl[0];
    walS0 = walG[(bt0 + t0) * 256 + ((tid & 3) << 6) + cwal];
    xpS0 = XP[(bt0 + t0) * 256 + tid];
    roeoS0 = Ro[(bt0 + t0) * C_ + croeo] | (Eo[(bt0 + t0) * C_ + croeo] << 8);
  }
  if (nT > 1) {
    const int t1 = sh_tl[1];
    walS1 = walG[(bt0 + t1) * 256 + ((tid & 3) << 6) + cwal];
    xpS1 = XP[(bt0 + t1) * 256 + tid];
    roeoS1 = Ro[(bt0 + t1) * C_ + croeo] | (Eo[(bt0 + t1) * C_ + croeo] << 8);
  }

  auto do_step = [&](int k, float& walS, float& xpS, int& roeoS) {
    const size_t bt = bt0 + sh_tl[k];
    const int roeoCur = roeoS;  // consume before the k+2 reload overwrites

    // ---- A: prev partials from mtreg (pure VALU) -> shp ----
    float a0 = 0.f, a1 = 0.f, a2 = 0.f, a3 = 0.f;
#pragma unroll
    for (int q = 0; q < 16; ++q) {
      const float mq = mtreg[q];
      a0 = fmaf(rlane(walS, 4 * q + 0), mq, a0);
      a1 = fmaf(rlane(walS, 4 * q + 1), mq, a1);
      a2 = fmaf(rlane(walS, 4 * q + 2), mq, a2);
      a3 = fmaf(rlane(walS, 4 * q + 3), mq, a3);
    }
    shp[w][0 * 64 + lane] = a0;
    shp[w][1 * 64 + lane] = a1;
    shp[w][2 * 64 + lane] = a2;
    shp[w][3 * 64 + lane] = a3;
    bar_lds();

    // ---- B1: prevX = prev[tid]; K-split h2h partials (RL 1:4 FMA) ----
    const float prevX = ((shp[0][tid] + shp[1][tid]) +
                         (shp[2][tid] + shp[3][tid]));  // = prev[64w + lane]
    float p0 = 0.f, p1 = 0.f, p2 = 0.f, p3 = 0.f;
#pragma unroll
    for (int i = 0; i < 64; ++i) {
      const float pk = rlane(prevX, i);  // prev[64w + i], wave-uniform
      p0 = fmaf(pk, ureg[i], p0);
      p1 = fmaf(pk, ureg[64 + i], p1);
      p2 = fmaf(pk, ureg[128 + i], p2);
      p3 = fmaf(pk, ureg[192 + i], p3);
    }
    pBred[w][0 * 64 + lane] = p0;
    pBred[w][1 * 64 + lane] = p1;
    pBred[w][2 * 64 + lane] = p2;
    pBred[w][3 * 64 + lane] = p3;
    bar_lds();

    // ---- B2: reduce h2h; gates; hnew; reload parity set for t_{k+2} ----
    const float h2h = ((pBred[0][tid] + pBred[1][tid]) +
                       (pBred[2][tid] + pBred[3][tid]));
    const float g1 = xpS + h2h + breg;
    const float rg = 1.f / (1.f + __expf(-g1));
    const float targ = xpS + rg * h2h + breg;
    const float e2 = __expf(2.f * targ);
    const float ht = 1.f - 2.f / (e2 + 1.f);  // tanh
    const float hn = (1.f - rg) * prevX + rg * ht;
    sh_hnew[tid] = hn;
    hbuf[bt * OUT_ + tid] = hn;
    if (k + 2 < nT) {
      const int t2 = sh_tl[k + 2];
      walS = walG[(bt0 + t2) * 256 + ((tid & 3) << 6) + cwal];
      xpS = XP[(bt0 + t2) * 256 + tid];
      roeoS = Ro[(bt0 + t2) * C_ + croeo] | (Eo[(bt0 + t2) * C_ + croeo] << 8);
    }
    bar_lds();

    // ---- C: mtreg select-update (hnew via 4 conflict-free b32 reads) ----
    const float h0 = sh_hnew[0 * 64 + lane];
    const float h1 = sh_hnew[1 * 64 + lane];
    const float h2 = sh_hnew[2 * 64 + lane];
    const float h3 = sh_hnew[3 * 64 + lane];
#pragma unroll
    for (int q = 0; q < 16; ++q) {
      const int re = rlane_i(roeoCur, q);   // uniform: ro | eo<<8
      const int ro = re & 0xFF;
      const float ha = (ro & 1) ? h1 : h0;
      const float hb = (ro & 1) ? h3 : h2;
      const float hs = (ro & 2) ? hb : ha;
      mtreg[q] = (re & 0x100) ? hs : mtreg[q];
    }
    // no barrier: next A only writes shp (last read pre-bar2); sh_hnew next
    // written in B2(k+1), two barriers away.
  };

  for (int k = 0; k < nT; k += 2) {
    do_step(k, walS0, xpS0, roeoS0);
    if (k + 1 < nT) do_step(k + 1, walS1, xpS1, roeoS1);
  }
}

// ---------------------------------------------------------------------------
// memsB: mems[b,t,c,:] = hbuf(tau)[ro(tau,c)*64+:], tau = last step<=t with
// M&Eo, else 0. One block per (b,c).
__global__ __launch_bounds__(512) void memsB(const int* __restrict__ M,
                                             const int* __restrict__ Eo,
                                             const int* __restrict__ Ro,
                                             const float* __restrict__ hbuf,
                                             float* __restrict__ mems) {
  __shared__ int lastA[T_];
  const int tid = threadIdx.x;
  const int b = blockIdx.x >> 6;
  const int c = blockIdx.x & 63;
  const size_t bt0 = (size_t)b * T_;
  {
    const int upd = M[bt0 + tid] & Eo[(bt0 + tid) * C_ + c];
    lastA[tid] = upd ? tid : -1;
  }
  __syncthreads();
  for (int off = 1; off < T_; off <<= 1) {
    const int u = (tid >= off) ? lastA[tid - off] : -1;
    const int v = lastA[tid];
    __syncthreads();
    lastA[tid] = (u > v) ? u : v;
    __syncthreads();
  }
  const int d = tid & 63;
  const int t8 = tid >> 6;
  for (int tt = 0; tt < 64; ++tt) {
    const int t = (tt << 3) + t8;
    const int tau = lastA[t];
    float v = 0.f;
    if (tau >= 0) {
      const int rc = Ro[(bt0 + tau) * C_ + c];
      v = hbuf[(bt0 + tau) * OUT_ + (rc << 6) + d];
    }
    mems[((bt0 + t) * C_ + c) * RD_ + d] = v;
  }
}

// ---------------------------------------------------------------------------
// outsC: outs[b,t,:] = hbuf(tauM), tauM = last M=1 step <= t, else 0.
// In place on hbuf/outs, descending t.
__global__ __launch_bounds__(512) void outsC(const int* __restrict__ M,
                                             float* __restrict__ outs) {
  __shared__ int lastM[T_];
  const int tid = threadIdx.x;
  const int b = blockIdx.x;
  const size_t bt0 = (size_t)b * T_;
  lastM[tid] = M[bt0 + tid] ? tid : -1;
  __syncthreads();
  for (int off = 1; off < T_; off <<= 1) {
    const int u = (tid >= off) ? lastM[tid - off] : -1;
    const int v = lastM[tid];
    __syncthreads();
    lastM[tid] = (u > v) ? u : v;
    __syncthreads();
  }
  const int j = tid & 255;
  const int th = tid >> 8;
  for (int k = 0; k < 256; ++k) {
    const int t = 511 - (k << 1) - th;
    const int tau = lastM[t];
    const float v = (tau >= 0) ? outs[(bt0 + tau) * OUT_ + j] : 0.f;
    __syncthreads();
    outs[(bt0 + t) * OUT_ + j] = v;
  }
}

// ---------------------------------------------------------------------------
extern "C" void kernel_launch(void* const* d_in, const int* in_sizes, int n_in,
                              void* d_out, int out_size, void* d_ws, size_t ws_size,
                              hipStream_t stream) {
  const float* X = (const float*)d_in[0];
  const int* M = (const int*)d_in[1];
  const int* Ei = (const int*)d_in[2];
  const int* Eo = (const int*)d_in[3];
  const int* Ri = (const int*)d_in[4];
  const int* Ro = (const int*)d_in[5];
  const float* W = (const float*)d_in[6];
  const float* U = (const float*)d_in[7];
  const float* Bv = (const float*)d_in[8];
  const float* Watt = (const float*)d_in[9];

  float* outs = (float*)d_out;
  float* mems = outs + (size_t)B_ * T_ * OUT_;
  float* aggs = mems + (size_t)B_ * T_ * C_ * RD_;
  float* XP = (float*)d_ws;   // 16.8 MB scratch
  float* hbuf = outs;         // hnew history aliases outs (outsC finalizes)
  float* walG = mems;         // alpha scratch aliases mems (memsB overwrites)

  xpre_kernel<<<dim3(B_ * T_ / 32), dim3(256), 0, stream>>>(X, W, XP);
  attnK<<<dim3(B_ * T_ / 4), dim3(256), 0, stream>>>(X, Ri, Ei, Watt, walG, aggs);
  gruA<<<dim3(B_), dim3(256), 0, stream>>>(M, Eo, Ro, U, Bv, XP, walG, hbuf);
  memsB<<<dim3(B_ * C_), dim3(512), 0, stream>>>(M, Eo, Ro, hbuf, mems);
  outsC<<<dim3(B_), dim3(512), 0, stream>>>(M, outs);
}